// Round 17
// baseline (758.692 us; speedup 1.0000x reference)
//
#include <hip/hip_runtime.h>
#include <hip/hip_bf16.h>

// Problem constants (RWKV-7 Tmix: B=2, T=1024, C=2048, H=32, N=64)
#define BB 2
#define TT 1024
#define CC 2048
#define HH 32
#define BT 2048          // BB*TT tokens
#define GN_EPS 6.4e-4f   // 1e-5 * 8^2

typedef __attribute__((ext_vector_type(8))) __bf16 bf16x8;
typedef __attribute__((ext_vector_type(4))) float f32x4;

__device__ __forceinline__ float sigf(float x) { return 1.0f / (1.0f + expf(-x)); }

__device__ __forceinline__ void split_bf16(float x, __hip_bfloat16& hi, __hip_bfloat16& lo) {
  __hip_bfloat16 h = __float2bfloat16(x);
  hi = h;
  lo = __float2bfloat16(x - __bfloat162float(h));
}

__device__ __forceinline__ unsigned short bfb(float x) {
  union { __hip_bfloat16 h; unsigned short u; } cv;
  cv.h = __float2bfloat16(x);
  return cv.u;
}
__device__ __forceinline__ void splitu(float x, unsigned short& hi, unsigned short& lo) {
  union { __hip_bfloat16 h; unsigned short u; } cv;
  cv.h = __float2bfloat16(x);
  hi = cv.u;
  lo = bfb(x - __bfloat162float(cv.h));
}

// Sum over each aligned 16-lane group, pure DPP (no LDS pipe on the chain).
__device__ __forceinline__ float red16(float x) {
  x += __int_as_float(__builtin_amdgcn_update_dpp(
      0, __float_as_int(x), 0xB1 /*quad_perm [1,0,3,2]*/, 0xF, 0xF, true));
  x += __int_as_float(__builtin_amdgcn_update_dpp(
      0, __float_as_int(x), 0x4E /*quad_perm [2,3,0,1]*/, 0xF, 0xF, true));
  x += __int_as_float(__builtin_amdgcn_update_dpp(
      0, __float_as_int(x), 0x141 /*row_half_mirror*/, 0xF, 0xF, true));
  x += __int_as_float(__builtin_amdgcn_update_dpp(
      0, __float_as_int(x), 0x140 /*row_mirror*/, 0xF, 0xF, true));
  return x;
}

// ---------------------------------------------------------------------------
// K1: token shift + six lerped projections — 4-wide vectorized (r14 winner).
// ---------------------------------------------------------------------------
__global__ __launch_bounds__(256) void k_prepx(
    const float* __restrict__ hid, const float* __restrict__ shift,
    const float* __restrict__ xrc, const float* __restrict__ xwc,
    const float* __restrict__ xkc, const float* __restrict__ xvc,
    const float* __restrict__ xac, const float* __restrict__ xgc,
    __hip_bfloat16* __restrict__ xrh, __hip_bfloat16* __restrict__ xrl,
    __hip_bfloat16* __restrict__ xw,
    __hip_bfloat16* __restrict__ xkh, __hip_bfloat16* __restrict__ xkl,
    __hip_bfloat16* __restrict__ xvh, __hip_bfloat16* __restrict__ xvl,
    __hip_bfloat16* __restrict__ xa, __hip_bfloat16* __restrict__ xg) {
  int i4 = (blockIdx.x * 256 + threadIdx.x) * 4;   // < BT*CC
  int c  = i4 & (CC - 1);
  int bt = i4 >> 11;
  int t  = bt & (TT - 1);
  int b  = bt >> 10;
  float4 hc = *(const float4*)&hid[i4];
  float4 hp = (t == 0) ? *(const float4*)&shift[b * CC + c]
                       : *(const float4*)&hid[i4 - CC];
  float xxv[4] = {hp.x - hc.x, hp.y - hc.y, hp.z - hc.z, hp.w - hc.w};
  float hcv[4] = {hc.x, hc.y, hc.z, hc.w};
  float4 crv = *(const float4*)&xrc[c];
  float4 cwv = *(const float4*)&xwc[c];
  float4 ckv = *(const float4*)&xkc[c];
  float4 cvv = *(const float4*)&xvc[c];
  float4 cav = *(const float4*)&xac[c];
  float4 cgv = *(const float4*)&xgc[c];
  float cr[4] = {crv.x, crv.y, crv.z, crv.w};
  float cw[4] = {cwv.x, cwv.y, cwv.z, cwv.w};
  float ck[4] = {ckv.x, ckv.y, ckv.z, ckv.w};
  float cv[4] = {cvv.x, cvv.y, cvv.z, cvv.w};
  float ca[4] = {cav.x, cav.y, cav.z, cav.w};
  float cg[4] = {cgv.x, cgv.y, cgv.z, cgv.w};
  ushort4 rh, rl, kh, kl, vh, vl, wv, av, gv;
  unsigned short* prh = (unsigned short*)&rh;
  unsigned short* prl = (unsigned short*)&rl;
  unsigned short* pkh = (unsigned short*)&kh;
  unsigned short* pkl = (unsigned short*)&kl;
  unsigned short* pvh = (unsigned short*)&vh;
  unsigned short* pvl = (unsigned short*)&vl;
  unsigned short* pw  = (unsigned short*)&wv;
  unsigned short* pa  = (unsigned short*)&av;
  unsigned short* pg  = (unsigned short*)&gv;
#pragma unroll
  for (int j = 0; j < 4; ++j) {
    splitu(fmaf(xxv[j], cr[j], hcv[j]), prh[j], prl[j]);
    splitu(fmaf(xxv[j], ck[j], hcv[j]), pkh[j], pkl[j]);
    splitu(fmaf(xxv[j], cv[j], hcv[j]), pvh[j], pvl[j]);
    pw[j] = bfb(fmaf(xxv[j], cw[j], hcv[j]));
    pa[j] = bfb(fmaf(xxv[j], ca[j], hcv[j]));
    pg[j] = bfb(fmaf(xxv[j], cg[j], hcv[j]));
  }
  *(ushort4*)&xrh[i4] = rh; *(ushort4*)&xrl[i4] = rl;
  *(ushort4*)&xkh[i4] = kh; *(ushort4*)&xkl[i4] = kl;
  *(ushort4*)&xvh[i4] = vh; *(ushort4*)&xvl[i4] = vl;
  *(ushort4*)&xw[i4]  = wv; *(ushort4*)&xa[i4]  = av;
  *(ushort4*)&xg[i4]  = gv;
}

// ---------------------------------------------------------------------------
// K2: f32 -> hi+lo bf16 split for all four big weights, 4-wide vectorized.
// ---------------------------------------------------------------------------
__global__ __launch_bounds__(256) void k_cvt2x4(
    const float* __restrict__ i0, const float* __restrict__ i1,
    const float* __restrict__ i2, const float* __restrict__ i3,
    __hip_bfloat16* __restrict__ h0, __hip_bfloat16* __restrict__ l0,
    __hip_bfloat16* __restrict__ h1, __hip_bfloat16* __restrict__ l1,
    __hip_bfloat16* __restrict__ h2, __hip_bfloat16* __restrict__ l2,
    __hip_bfloat16* __restrict__ h3, __hip_bfloat16* __restrict__ l3) {
  int i4 = (blockIdx.x * 256 + threadIdx.x) * 4;
  int w = blockIdx.y;
  const float* in = (w == 0) ? i0 : (w == 1) ? i1 : (w == 2) ? i2 : i3;
  __hip_bfloat16* oh = (w == 0) ? h0 : (w == 1) ? h1 : (w == 2) ? h2 : h3;
  __hip_bfloat16* ol = (w == 0) ? l0 : (w == 1) ? l1 : (w == 2) ? l2 : l3;
  float4 v = *(const float4*)&in[i4];
  float vv[4] = {v.x, v.y, v.z, v.w};
  ushort4 hv, lv;
  unsigned short* ph = (unsigned short*)&hv;
  unsigned short* pl = (unsigned short*)&lv;
#pragma unroll
  for (int j = 0; j < 4; ++j) splitu(vv[j], ph[j], pl[j]);
  *(ushort4*)&oh[i4] = hv;
  *(ushort4*)&ol[i4] = lv;
}

// ---------------------------------------------------------------------------
// K3: fused transpose-convert of the 4 stage-1 "up" weights (one dispatch).
// ---------------------------------------------------------------------------
__global__ __launch_bounds__(256) void k_tr4(
    const float* __restrict__ w1, const float* __restrict__ a1,
    const float* __restrict__ v1, const float* __restrict__ g1,
    __hip_bfloat16* __restrict__ w1t, __hip_bfloat16* __restrict__ a1t,
    __hip_bfloat16* __restrict__ v1t, __hip_bfloat16* __restrict__ g1t) {
  int i = blockIdx.x * 256 + threadIdx.x;   // < 128*2048 max
  int y = blockIdx.y;
  const float* in; __hip_bfloat16* out; int N0, NP;
  if (y == 0)      { in = w1; out = w1t; N0 = 64;  NP = 64;  }
  else if (y == 1) { in = a1; out = a1t; N0 = 64;  NP = 64;  }
  else if (y == 2) { in = v1; out = v1t; N0 = 32;  NP = 64;  }
  else             { in = g1; out = g1t; N0 = 128; NP = 128; }
  if (i >= NP * 2048) return;
  int n = i >> 11;
  int k = i & 2047;
  float v = (n < N0) ? in[k * N0 + n] : 0.0f;
  out[i] = __float2bfloat16(v);
}

// ---------------------------------------------------------------------------
// K3b: fused transpose+split of the 4 stage-2 "down" weights (one dispatch).
// ---------------------------------------------------------------------------
__global__ __launch_bounds__(256) void k_trs4(
    const float* __restrict__ w2, const float* __restrict__ a2,
    const float* __restrict__ v2, const float* __restrict__ g2,
    __hip_bfloat16* __restrict__ w2th, __hip_bfloat16* __restrict__ w2tl,
    __hip_bfloat16* __restrict__ a2th, __hip_bfloat16* __restrict__ a2tl,
    __hip_bfloat16* __restrict__ v2th, __hip_bfloat16* __restrict__ v2tl,
    __hip_bfloat16* __restrict__ g2th, __hip_bfloat16* __restrict__ g2tl) {
  int i = blockIdx.x * 256 + threadIdx.x;   // < CC*128 max
  int y = blockIdx.y;
  const float* in; __hip_bfloat16 *oh, *ol; int N0, lgK;
  if (y == 0)      { in = w2; oh = w2th; ol = w2tl; N0 = 64;  lgK = 6; }
  else if (y == 1) { in = a2; oh = a2th; ol = a2tl; N0 = 64;  lgK = 6; }
  else if (y == 2) { in = v2; oh = v2th; ol = v2tl; N0 = 32;  lgK = 6; }
  else             { in = g2; oh = g2th; ol = g2tl; N0 = 128; lgK = 7; }
  if (i >= (CC << lgK)) return;
  int n = i >> lgK;
  int k = i & ((1 << lgK) - 1);
  float v = (k < N0) ? in[k * CC + n] : 0.0f;
  split_bf16(v, oh[i], ol[i]);
}

// ---------------------------------------------------------------------------
// K4: fused stage-1 LoRA GEMM, LDS-staged (r11 structure + r15 swizzle).
// ---------------------------------------------------------------------------
__global__ __launch_bounds__(256, 4) void k_lora1(
    const __hip_bfloat16* __restrict__ xw, const __hip_bfloat16* __restrict__ xa,
    const __hip_bfloat16* __restrict__ xv, const __hip_bfloat16* __restrict__ xg,
    const __hip_bfloat16* __restrict__ w1t, const __hip_bfloat16* __restrict__ a1t,
    const __hip_bfloat16* __restrict__ v1t, const __hip_bfloat16* __restrict__ g1t,
    float* __restrict__ h1w, float* __restrict__ h1a,
    float* __restrict__ h1v, float* __restrict__ h1g) {
  __shared__ __align__(16) __hip_bfloat16 sA[2][64 * 32], sB[2][64 * 32];
  int tid  = threadIdx.x;
  int lane = tid & 63;
  int wv   = tid >> 6;
  int l15  = lane & 15;
  int quad = lane >> 4;
  int m0 = blockIdx.x * 64;
  int bly = blockIdx.y;

  const __hip_bfloat16* Ab;
  const __hip_bfloat16* Bb;
  float* Ob;
  int os, cb;
  if (bly == 0)      { Ab = xw; Bb = w1t;            Ob = h1w; os = 64;  cb = 0;  }
  else if (bly == 1) { Ab = xa; Bb = a1t;            Ob = h1a; os = 64;  cb = 0;  }
  else if (bly == 2) { Ab = xv; Bb = v1t;            Ob = h1v; os = 64;  cb = 0;  }
  else if (bly == 3) { Ab = xg; Bb = g1t;            Ob = h1g; os = 128; cb = 0;  }
  else               { Ab = xg; Bb = g1t + 64 * CC;  Ob = h1g; os = 128; cb = 64; }

  int srow = wv * 16 + (lane >> 2);
  int scol = (((lane & 3) ^ ((lane >> 2) & 3)) * 8);   // inverse-swizzled src
  const __hip_bfloat16* gA = Ab + (size_t)(m0 + srow) * CC + scol;
  const __hip_bfloat16* gB = Bb + (size_t)srow * CC + scol;

  f32x4 z = {0.f, 0.f, 0.f, 0.f};
  f32x4 acc0 = z, acc1 = z, acc2 = z, acc3 = z;

  int sw = (quad ^ (l15 & 3)) * 8;                     // swizzled read col
  int aoff = (wv * 16 + l15) * 32 + sw;
  int boff = l15 * 32 + sw;

#define STAGE1(BUF, KO)                                                      \
  { unsigned db_ = (unsigned)(BUF) * 4096u + (unsigned)wv * 1024u;           \
    __builtin_amdgcn_global_load_lds(                                        \
        (const __attribute__((address_space(1))) void*)(gA + (KO)),          \
        (__attribute__((address_space(3))) void*)((char*)sA + db_), 16, 0, 0);\
    __builtin_amdgcn_global_load_lds(                                        \
        (const __attribute__((address_space(1))) void*)(gB + (KO)),          \
        (__attribute__((address_space(3))) void*)((char*)sB + db_), 16, 0, 0);}

  STAGE1(0, 0)
  __syncthreads();

  for (int k0 = 0; k0 < CC; k0 += 32) {
    int cur = (k0 >> 5) & 1;
    if (k0 + 32 < CC) STAGE1(cur ^ 1, k0 + 32)

    const __hip_bfloat16* pA_ = &sA[cur][0];
    const __hip_bfloat16* pB_ = &sB[cur][0];
    bf16x8 av = *(const bf16x8*)(pA_ + aoff);
    bf16x8 b0 = *(const bf16x8*)(pB_ + boff);
    bf16x8 b1 = *(const bf16x8*)(pB_ + boff + 16 * 32);
    bf16x8 b2 = *(const bf16x8*)(pB_ + boff + 32 * 32);
    bf16x8 b3 = *(const bf16x8*)(pB_ + boff + 48 * 32);

    acc0 = __builtin_amdgcn_mfma_f32_16x16x32_bf16(av, b0, acc0, 0, 0, 0);
    acc1 = __builtin_amdgcn_mfma_f32_16x16x32_bf16(av, b1, acc1, 0, 0, 0);
    acc2 = __builtin_amdgcn_mfma_f32_16x16x32_bf16(av, b2, acc2, 0, 0, 0);
    acc3 = __builtin_amdgcn_mfma_f32_16x16x32_bf16(av, b3, acc3, 0, 0, 0);

    __syncthreads();
  }
#undef STAGE1

  int row0 = m0 + wv * 16 + quad * 4;
  int colb = cb + l15;
#pragma unroll
  for (int r = 0; r < 4; ++r) {
    Ob[(size_t)(row0 + r) * os + colb +  0] = acc0[r];
    Ob[(size_t)(row0 + r) * os + colb + 16] = acc1[r];
    Ob[(size_t)(row0 + r) * os + colb + 32] = acc2[r];
    Ob[(size_t)(row0 + r) * os + colb + 48] = acc3[r];
  }
}

// ---------------------------------------------------------------------------
// K4b body — ROUND-24: T3/T4-lite. r16 PMC proved bank conflicts are
// DMA-generated (swizzle left the counter bit-identical) and off the
// critical path; the real 2-phase stall is __syncthreads' implicit
// vmcnt(0) DRAIN after each 6-DMA stage (m233). Fix: 3-buffer ring +
// counted s_waitcnt vmcnt(6) + RAW s_barrier (m201/m218 mechanism):
// each wave counts ITS OWN 6 DMAs (vmcnt(6) = STAGE(i) landed, STAGE(i+1)
// still in flight), then the barrier publishes all waves' stages. Ledger:
// prologue STAGE(0),STAGE(1); iter i: wait(6) -> barrier -> STAGE(i+2)
// into slot (i+2)%3 (overwrites b_{i-1}, whose reads finished before this
// barrier) -> compute b_i. One barrier/step, zero drains, stage latency
// hidden ~2 K-steps of MFMA. LDS 72KB -> 2 blocks/CU (256,2).
// ---------------------------------------------------------------------------
__device__ __forceinline__ void gemm_bt3_body(
    const __hip_bfloat16* __restrict__ Ah, const __hip_bfloat16* __restrict__ Al,
    const __hip_bfloat16* __restrict__ Bh, const __hip_bfloat16* __restrict__ Bl,
    float* __restrict__ Cm, int Nn, int K) {
  __shared__ __align__(16) __hip_bfloat16 sAh[3][64 * 32],  sAl[3][64 * 32];
  __shared__ __align__(16) __hip_bfloat16 sBh[3][128 * 32], sBl[3][128 * 32];
  int tid  = threadIdx.x;
  int lane = tid & 63;
  int wv   = tid >> 6;
  int l15  = lane & 15;
  int quad = lane >> 4;
  int m0 = blockIdx.x * 64;
  int n0 = blockIdx.y * 128;

  int srowA = wv * 16 + (lane >> 2);
  int srowB = wv * 32 + (lane >> 2);
  int scol  = (((lane & 3) ^ ((lane >> 2) & 3)) * 8);  // inverse-swizzled src
  const __hip_bfloat16* gAh  = Ah + (size_t)(m0 + srowA) * K + scol;
  const __hip_bfloat16* gAl  = Al + (size_t)(m0 + srowA) * K + scol;
  const __hip_bfloat16* gBh0 = Bh + (size_t)(n0 + srowB) * K + scol;
  const __hip_bfloat16* gBh1 = Bh + (size_t)(n0 + srowB + 16) * K + scol;
  const __hip_bfloat16* gBl0 = Bl + (size_t)(n0 + srowB) * K + scol;
  const __hip_bfloat16* gBl1 = Bl + (size_t)(n0 + srowB + 16) * K + scol;

  f32x4 z = {0.f, 0.f, 0.f, 0.f};
  f32x4 acc[8];
#pragma unroll
  for (int j = 0; j < 8; ++j) acc[j] = z;

  int sw = (quad ^ (l15 & 3)) * 8;                     // swizzled read col
  int aoff = (wv * 16 + l15) * 32 + sw;
  int boff = l15 * 32 + sw;

#define STAGE(BUF, KO)                                                       \
  { unsigned dA_ = (unsigned)(BUF) * 4096u + (unsigned)wv * 1024u;           \
    unsigned dB_ = (unsigned)(BUF) * 8192u + (unsigned)wv * 2048u;           \
    __builtin_amdgcn_global_load_lds(                                        \
        (const __attribute__((address_space(1))) void*)(gAh + (KO)),         \
        (__attribute__((address_space(3))) void*)((char*)sAh + dA_), 16, 0, 0);\
    __builtin_amdgcn_global_load_lds(                                        \
        (const __attribute__((address_space(1))) void*)(gAl + (KO)),         \
        (__attribute__((address_space(3))) void*)((char*)sAl + dA_), 16, 0, 0);\
    __builtin_amdgcn_global_load_lds(                                        \
        (const __attribute__((address_space(1))) void*)(gBh0 + (KO)),        \
        (__attribute__((address_space(3))) void*)((char*)sBh + dB_), 16, 0, 0);\
    __builtin_amdgcn_global_load_lds(                                        \
        (const __attribute__((address_space(1))) void*)(gBh1 + (KO)),        \
        (__attribute__((address_space(3))) void*)((char*)sBh + dB_ + 1024u), 16, 0, 0);\
    __builtin_amdgcn_global_load_lds(                                        \
        (const __attribute__((address_space(1))) void*)(gBl0 + (KO)),        \
        (__attribute__((address_space(3))) void*)((char*)sBl + dB_), 16, 0, 0);\
    __builtin_amdgcn_global_load_lds(                                        \
        (const __attribute__((address_space(1))) void*)(gBl1 + (KO)),        \
        (__attribute__((address_space(3))) void*)((char*)sBl + dB_ + 1024u), 16, 0, 0);}

  int nk = K >> 5;                       // K-steps (BK=32); K multiple of 64
  STAGE(0, 0)
  STAGE(1, 32)

  for (int i = 0; i < nk; ++i) {
    // STAGE(i) landed (STAGE(i+1)'s 6 DMAs may still fly); counted wait =
    // no drain. Last step: nothing newer outstanding -> vmcnt(0) ≡ exact.
    if (i + 1 < nk) {
      asm volatile("s_waitcnt vmcnt(6)" ::: "memory");
    } else {
      asm volatile("s_waitcnt vmcnt(0)" ::: "memory");
    }
    __builtin_amdgcn_sched_barrier(0);
    __builtin_amdgcn_s_barrier();       // publishes all waves' STAGE(i)
    __builtin_amdgcn_sched_barrier(0);

    if (i + 2 < nk) {
      int sl = i + 2;
      sl = (sl >= 3) ? (sl % 3) : sl;
      STAGE(sl, (i + 2) * 32)           // overwrite b_{i-1}: reads done
    }
    __builtin_amdgcn_sched_barrier(0);

    int cur = i % 3;
    const __hip_bfloat16* pA_h = &sAh[cur][0];
    const __hip_bfloat16* pA_l = &sAl[cur][0];
    const __hip_bfloat16* pB_h = &sBh[cur][0];
    const __hip_bfloat16* pB_l = &sBl[cur][0];
    bf16x8 ah = *(const bf16x8*)(pA_h + aoff);
    bf16x8 al = *(const bf16x8*)(pA_l + aoff);
#pragma unroll
    for (int j = 0; j < 8; ++j) {
      bf16x8 bh = *(const bf16x8*)(pB_h + boff + j * 16 * 32);
      bf16x8 bl = *(const bf16x8*)(pB_l + boff + j * 16 * 32);
      acc[j] = __builtin_amdgcn_mfma_f32_16x16x32_bf16(ah, bh, acc[j], 0, 0, 0);
      acc[j] = __builtin_amdgcn_mfma_f32_16x16x32_bf16(ah, bl, acc[j], 0, 0, 0);
      acc[j] = __builtin_amdgcn_mfma_f32_16x16x32_bf16(al, bh, acc[j], 0, 0, 0);
    }
    // no trailing barrier: next iteration's vmcnt+barrier is the fence.
  }
#undef STAGE

  int row0 = m0 + wv * 16 + quad * 4;
#pragma unroll
  for (int j = 0; j < 8; ++j) {
    int colb = n0 + j * 16 + l15;
#pragma unroll
    for (int r = 0; r < 4; ++r)
      Cm[(size_t)(row0 + r) * Nn + colb] = acc[j][r];
  }
}

// standalone (Wo output GEMM)
__global__ __launch_bounds__(256, 2) void k_gemm_bt3(
    const __hip_bfloat16* __restrict__ Ah, const __hip_bfloat16* __restrict__ Al,
    const __hip_bfloat16* __restrict__ Bh, const __hip_bfloat16* __restrict__ Bl,
    float* __restrict__ Cm, int M, int Nn, int K) {
  gemm_bt3_body(Ah, Al, Bh, Bl, Cm, Nn, K);
}

// 3 big input GEMMs (r/k/v) fused into one dispatch, grid z = slice.
__global__ __launch_bounds__(256, 2) void k_gemm_big3(
    const __hip_bfloat16* __restrict__ Ah0, const __hip_bfloat16* __restrict__ Al0,
    const __hip_bfloat16* __restrict__ Bh0, const __hip_bfloat16* __restrict__ Bl0,
    float* __restrict__ C0,
    const __hip_bfloat16* __restrict__ Ah1, const __hip_bfloat16* __restrict__ Al1,
    const __hip_bfloat16* __restrict__ Bh1, const __hip_bfloat16* __restrict__ Bl1,
    float* __restrict__ C1,
    const __hip_bfloat16* __restrict__ Ah2, const __hip_bfloat16* __restrict__ Al2,
    const __hip_bfloat16* __restrict__ Bh2, const __hip_bfloat16* __restrict__ Bl2,
    float* __restrict__ C2) {
  int zz = blockIdx.z;
  const __hip_bfloat16* Ah = (zz == 0) ? Ah0 : (zz == 1) ? Ah1 : Ah2;
  const __hip_bfloat16* Al = (zz == 0) ? Al0 : (zz == 1) ? Al1 : Al2;
  const __hip_bfloat16* Bh = (zz == 0) ? Bh0 : (zz == 1) ? Bh1 : Bh2;
  const __hip_bfloat16* Bl = (zz == 0) ? Bl0 : (zz == 1) ? Bl1 : Bl2;
  float* Cm = (zz == 0) ? C0 : (zz == 1) ? C1 : C2;
  gemm_bt3_body(Ah, Al, Bh, Bl, Cm, CC, CC);
}

// 4 stage-2 GEMMs fused into one dispatch, grid z = slice (K table).
__global__ __launch_bounds__(256, 2) void k_gemm_s2x4(
    const __hip_bfloat16* __restrict__ h1wh, const __hip_bfloat16* __restrict__ h1wl,
    const __hip_bfloat16* __restrict__ h1ah, const __hip_bfloat16* __restrict__ h1al,
    const __hip_bfloat16* __restrict__ h1vh, const __hip_bfloat16* __restrict__ h1vl,
    const __hip_bfloat16* __restrict__ h1gh, const __hip_bfloat16* __restrict__ h1gl,
    const __hip_bfloat16* __restrict__ w2th, const __hip_bfloat16* __restrict__ w2tl,
    const __hip_bfloat16* __restrict__ a2th, const __hip_bfloat16* __restrict__ a2tl,
    const __hip_bfloat16* __restrict__ v2th, const __hip_bfloat16* __restrict__ v2tl,
    const __hip_bfloat16* __restrict__ g2th, const __hip_bfloat16* __restrict__ g2tl,
    float* __restrict__ h2w, float* __restrict__ h2a,
    float* __restrict__ h2v, float* __restrict__ h2g) {
  int zz = blockIdx.z;
  const __hip_bfloat16* Ah = (zz == 0) ? h1wh : (zz == 1) ? h1ah : (zz == 2) ? h1vh : h1gh;
  const __hip_bfloat16* Al = (zz == 0) ? h1wl : (zz == 1) ? h1al : (zz == 2) ? h1vl : h1gl;
  const __hip_bfloat16* Bh = (zz == 0) ? w2th : (zz == 1) ? a2th : (zz == 2) ? v2th : g2th;
  const __hip_bfloat16* Bl = (zz == 0) ? w2tl : (zz == 1) ? a2tl : (zz == 2) ? v2tl : g2tl;
  float* Cm = (zz == 0) ? h2w : (zz == 1) ? h2a : (zz == 2) ? h2v : h2g;
  int K = (zz == 3) ? 128 : 64;
  gemm_bt3_body(Ah, Al, Bh, Bl, Cm, CC, K);
}

// ---------------------------------------------------------------------------
// K5: activations + hi/lo split of stage-1 LoRA outputs — 4-wide vectorized.
// ---------------------------------------------------------------------------
__global__ __launch_bounds__(256) void k_act2(
    const float* __restrict__ h1w, const float* __restrict__ h1a,
    const float* __restrict__ h1v, const float* __restrict__ h1g,
    __hip_bfloat16* __restrict__ wh, __hip_bfloat16* __restrict__ wl,
    __hip_bfloat16* __restrict__ ah, __hip_bfloat16* __restrict__ al,
    __hip_bfloat16* __restrict__ vh, __hip_bfloat16* __restrict__ vl,
    __hip_bfloat16* __restrict__ gh, __hip_bfloat16* __restrict__ gl) {
  int i4 = (blockIdx.x * 256 + threadIdx.x) * 4;   // over BT*128
  if (i4 < BT * 64) {
    float4 w = *(const float4*)&h1w[i4];
    float4 a = *(const float4*)&h1a[i4];
    float4 v = *(const float4*)&h1v[i4];
    float wvv[4] = {w.x, w.y, w.z, w.w};
    float avv[4] = {a.x, a.y, a.z, a.w};
    float vvv[4] = {v.x, v.y, v.z, v.w};
    ushort4 whv, wlv, ahv, alv, vhv, vlv;
    unsigned short* p0 = (unsigned short*)&whv;
    unsigned short* p1 = (unsigned short*)&wlv;
    unsigned short* p2 = (unsigned short*)&ahv;
    unsigned short* p3 = (unsigned short*)&alv;
    unsigned short* p4 = (unsigned short*)&vhv;
    unsigned short* p5 = (unsigned short*)&vlv;
#pragma unroll
    for (int j = 0; j < 4; ++j) {
      splitu(tanhf(wvv[j]), p0[j], p1[j]);
      splitu(avv[j], p2[j], p3[j]);
      splitu(vvv[j], p4[j], p5[j]);
    }
    *(ushort4*)&wh[i4] = whv; *(ushort4*)&wl[i4] = wlv;
    *(ushort4*)&ah[i4] = ahv; *(ushort4*)&al[i4] = alv;
    *(ushort4*)&vh[i4] = vhv; *(ushort4*)&vl[i4] = vlv;
  }
  float4 g = *(const float4*)&h1g[i4];
  float gvv[4] = {g.x, g.y, g.z, g.w};
  ushort4 ghv, glv;
  unsigned short* p6 = (unsigned short*)&ghv;
  unsigned short* p7 = (unsigned short*)&glv;
#pragma unroll
  for (int j = 0; j < 4; ++j) splitu(sigf(gvv[j]), p6[j], p7[j]);
  *(ushort4*)&gh[i4] = ghv; *(ushort4*)&gl[i4] = glv;
}

// ---------------------------------------------------------------------------
// K6: gates + kk-normalize + per-head bonus — 4-wide, red16 reductions.
// ---------------------------------------------------------------------------
__global__ __launch_bounds__(256) void k_gate(
    const float* __restrict__ h2w, const float* __restrict__ h2a,
    const float* __restrict__ h2v,
    const float* __restrict__ w0, const float* __restrict__ a0,
    const float* __restrict__ v0, const float* __restrict__ kkc,
    const float* __restrict__ kac, float* __restrict__ kbuf,
    float* __restrict__ vbuf, const float* __restrict__ vfirst,
    const float* __restrict__ rbuf, const float* __restrict__ rk,
    float* __restrict__ dec, float* __restrict__ aw,
    float* __restrict__ bw, float* __restrict__ bonb) {
  int i4 = (blockIdx.x * 256 + threadIdx.x) * 4;   // < BT*CC
  int c = i4 & (CC - 1);
  float4 kv4 = *(const float4*)&kbuf[i4];
  float4 vv4 = *(const float4*)&vbuf[i4];
  float4 vf4 = *(const float4*)&vfirst[i4];
  float4 hw4 = *(const float4*)&h2w[i4];
  float4 ha4 = *(const float4*)&h2a[i4];
  float4 hv4 = *(const float4*)&h2v[i4];
  float4 w04 = *(const float4*)&w0[c];
  float4 a04 = *(const float4*)&a0[c];
  float4 v04 = *(const float4*)&v0[c];
  float4 kk4 = *(const float4*)&kkc[c];
  float4 ka4 = *(const float4*)&kac[c];
  float4 rk4 = *(const float4*)&rk[c];
  float4 rb4 = *(const float4*)&rbuf[i4];
  float kv[4] = {kv4.x, kv4.y, kv4.z, kv4.w};
  float vv[4] = {vv4.x, vv4.y, vv4.z, vv4.w};
  float vf[4] = {vf4.x, vf4.y, vf4.z, vf4.w};
  float hw[4] = {hw4.x, hw4.y, hw4.z, hw4.w};
  float ha[4] = {ha4.x, ha4.y, ha4.z, ha4.w};
  float hv[4] = {hv4.x, hv4.y, hv4.z, hv4.w};
  float w0v[4] = {w04.x, w04.y, w04.z, w04.w};
  float a0v[4] = {a04.x, a04.y, a04.z, a04.w};
  float v0v[4] = {v04.x, v04.y, v04.z, v04.w};
  float kkv[4] = {kk4.x, kk4.y, kk4.z, kk4.w};
  float kav[4] = {ka4.x, ka4.y, ka4.z, ka4.w};
  float rkv[4] = {rk4.x, rk4.y, rk4.z, rk4.w};
  float rbv[4] = {rb4.x, rb4.y, rb4.z, rb4.w};
  float d_[4], as[4], vm[4], kfv[4], kku[4];
  float sl = 0.f, bl = 0.f;
#pragma unroll
  for (int j = 0; j < 4; ++j) {
    d_[j] = 0.60653065971f * sigf(w0v[j] + hw[j]);   // sigmoid * e^-0.5
    as[j] = sigf(a0v[j] + ha[j]);
    float vs = sigf(v0v[j] + hv[j]);
    vm[j] = vv[j] + (vf[j] - vv[j]) * vs;
    kfv[j] = kv[j] * (1.0f + kav[j] * (as[j] - 1.0f));
    kku[j] = kv[j] * kkv[j];
    sl = fmaf(kku[j], kku[j], sl);
    bl = fmaf(rbv[j] * kfv[j], rkv[j], bl);
  }
  float s = red16(sl);                 // per-head L2 (16 lanes x 4 cols)
  float nrm = fmaxf(sqrtf(s), 1e-12f);
  float bon = red16(bl);
  if ((threadIdx.x & 15) == 0) bonb[(i4 >> 11) * HH + (c >> 6)] = bon;
  float4 o0, o1, o2, o3, o4;
  float* q0 = (float*)&o0; float* q1 = (float*)&o1; float* q2 = (float*)&o2;
  float* q3 = (float*)&o3; float* q4 = (float*)&o4;
#pragma unroll
  for (int j = 0; j < 4; ++j) {
    float kkn = kku[j] / nrm;
    q0[j] = d_[j];
    q1[j] = -kkn;
    q2[j] = kkn * as[j];
    q3[j] = kfv[j];
    q4[j] = vm[j];
  }
  *(float4*)&dec[i4] = o0;
  *(float4*)&aw[i4]  = o1;
  *(float4*)&bw[i4]  = o2;
  *(float4*)&kbuf[i4] = o3;
  *(float4*)&vbuf[i4] = o4;
}

// ---------------------------------------------------------------------------
// K7: WKV7 scan — r13 counted-lgkm LDS-DMA-ring version (~180 µs), unchanged.
// ---------------------------------------------------------------------------
__global__ __launch_bounds__(64, 1) void k_scan(
    const float* __restrict__ rbuf, const float* __restrict__ kf,
    const float* __restrict__ dec, const float* __restrict__ aw,
    const float* __restrict__ bw, const float* __restrict__ vbuf,
    const float* __restrict__ st0, float* __restrict__ ybuf) {
  __shared__ __align__(16) char ldsbuf[16 * 2048];
  int blk = blockIdx.x;                     // 0..1023
  int xcd = blk & 7;
  int q   = blk >> 3;                       // 0..127
  int bh  = xcd * 8 + (q & 7);              // 16 rg-waves of a head share blk%8
  int rg  = q >> 3;                         // 0..15
  int b = bh >> 5, h = bh & 31;
  int lane = threadIdx.x;
  int l15  = lane & 15;
  int row  = rg * 4 + (lane >> 4);
  size_t tokbase = (size_t)b * TT * CC + h * 64;

  f32x4 S = *(const f32x4*)(st0 + ((size_t)bh * 64 + row) * 64 + l15 * 4);
  bool writer = (l15 == 0);
  float* yout = ybuf + tokbase + row;

  const float* g1 = (lane < 16 ? rbuf : lane < 32 ? kf : lane < 48 ? dec : aw)
                  + tokbase + l15 * 4;
  const float* g2 = (lane < 16) ? (bw + tokbase + l15 * 4)
                                : (vbuf + tokbase + rg * 4);

  unsigned lbase = (unsigned)(uintptr_t)(__attribute__((address_space(3))) char*)ldsbuf;
  unsigned larr = lbase + (unsigned)(l15 * 16);
  unsigned lvad = lbase + 1280u + (unsigned)((lane >> 4) * 4);

#define DMAQ(T)                                                              \
  { char* sb_ = ldsbuf + (((T) & 15) << 11);                                 \
    __builtin_amdgcn_global_load_lds(                                        \
        (const __attribute__((address_space(1))) void*)g1,                   \
        (__attribute__((address_space(3))) void*)sb_, 16, 0, 0);             \
    __builtin_amdgcn_global_load_lds(                                        \
        (const __attribute__((address_space(1))) void*)g2,                   \
        (__attribute__((address_space(3))) void*)(sb_ + 1024), 16, 0, 0);    \
    g1 += CC; g2 += CC; }

#define DSRD(RR, RK, RD, RA, RB, RV, T)                                      \
  { unsigned a_ = larr + (unsigned)(((T) & 15) << 11);                       \
    unsigned v_ = lvad + (unsigned)(((T) & 15) << 11);                       \
    asm volatile("ds_read_b128 %0, %1"             : "=v"(RR) : "v"(a_));    \
    asm volatile("ds_read_b128 %0, %1 offset:256"  : "=v"(RK) : "v"(a_));    \
    asm volatile("ds_read_b128 %0, %1 offset:512"  : "=v"(RD) : "v"(a_));    \
    asm volatile("ds_read_b128 %0, %1 offset:768"  : "=v"(RA) : "v"(a_));    \
    asm volatile("ds_read_b128 %0, %1 offset:1024" : "=v"(RB) : "v"(a_));    \
    asm volatile("ds_read_b32 %0, %1"              : "=v"(RV) : "v"(v_)); }

#define WVM(N) { asm volatile("s_waitcnt vmcnt(" #N ")" ::: "memory");       \
                 __builtin_amdgcn_sched_barrier(0); }
#define WLG    { asm volatile("s_waitcnt lgkmcnt(0)" ::: "memory");          \
                 __builtin_amdgcn_sched_barrier(0); }
#define WLG6   { asm volatile("s_waitcnt lgkmcnt(6)" ::: "memory");          \
                 __builtin_amdgcn_sched_barrier(0); }

#define STEPR(RR, RK, RD, RA, RB, RV, T)                                     \
  { float sa = fmaf(S.w, RA.w, fmaf(S.z, RA.z,                               \
               fmaf(S.y, RA.y, S.x * RA.x)));                                \
    sa = red16(sa);                                                          \
    float vv = RV;                                                           \
    S.x = fmaf(S.x, RD.x, fmaf(sa, RB.x, vv * RK.x));                        \
    S.y = fmaf(S.y, RD.y, fmaf(sa, RB.y, vv * RK.y));                        \
    S.z = fmaf(S.z, RD.z, fmaf(sa, RB.z, vv * RK.z));                        \
    S.w = fmaf(S.w, RD.w, fmaf(sa, RB.w, vv * RK.w));                        \
    float y = fmaf(S.w, RR.w, fmaf(S.z, RR.z,                                \
              fmaf(S.y, RR.y, S.x * RR.x)));                                 \
    y = red16(y);                                                            \
    if (writer) yout[(size_t)(T) * CC] = y; }

  for (int tt = 0; tt < 16; ++tt) DMAQ(tt)

  f32x4 Ar, Ak, Ad, Aa, Ab; float Av;
  f32x4 Br, Bk, Bd, Ba, Bb; float Bv;

  WVM(24)
  DSRD(Ar, Ak, Ad, Aa, Ab, Av, 0)
  WLG
  DSRD(Br, Bk, Bd, Ba, Bb, Bv, 1)

  int t = 0;
  for (; t < TT - 16; t += 2) {
    DMAQ(t + 16)
    STEPR(Ar, Ak, Ad, Aa, Ab, Av, t)
    DSRD(Ar, Ak, Ad, Aa, Ab, Av, t + 2)
    WLG6
    DMAQ(t + 17)
    STEPR(Br, Bk, Bd, Ba, Bb, Bv, t + 1)
    DSRD(Br, Bk, Bd, Ba, Bb, Bv, t + 3)
    WLG6
  }
  for (; t < TT - 2; t += 2) {
    STEPR(Ar, Ak, Ad, Aa, Ab, Av, t)
    DSRD(Ar, Ak, Ad, Aa, Ab, Av, t + 2)
    WLG6
    STEPR(Br, Bk, Bd, Ba, Bb, Bv, t + 1)
    if (t + 3 < TT) DSRD(Br, Bk, Bd, Ba, Bb, Bv, t + 3)
    WLG6
  }
  STEPR(Ar, Ak, Ad, Aa, Ab, Av, TT - 2)
  WLG
  STEPR(Br, Bk, Bd, Ba, Bb, Bv, TT - 1)
#undef DMAQ
#undef DSRD
#undef WVM
#undef WLG
#undef WLG6
#undef STEPR
}

// ---------------------------------------------------------------------------
// K8: post-scan epilogue — 4-wide, red16 statistics.
// ---------------------------------------------------------------------------
__global__ __launch_bounds__(256) void k_post(
    const float* __restrict__ ybuf, const float* __restrict__ vb,
    const float* __restrict__ gvb, const float* __restrict__ bonb,
    const float* __restrict__ gnw, const float* __restrict__ gnb,
    __hip_bfloat16* __restrict__ xoh, __hip_bfloat16* __restrict__ xol) {
  int gid = blockIdx.x * 16 + (threadIdx.x >> 4);   // 0..BT*HH-1
  int l15 = threadIdx.x & 15;
  int bt = gid >> 5, h = gid & 31;
  size_t base = (size_t)bt * CC + h * 64 + l15 * 4;
  float4 y4 = *(const float4*)&ybuf[base];
  float yv[4] = {y4.x, y4.y, y4.z, y4.w};
  float s1 = yv[0] + yv[1] + yv[2] + yv[3];
  float s2 = fmaf(yv[0], yv[0], fmaf(yv[1], yv[1],
             fmaf(yv[2], yv[2], yv[3] * yv[3])));
  s1 = red16(s1);
  s2 = red16(s2);
  float mean = s1 * (1.0f / 64.0f);
  float var  = s2 * (1.0f / 64.0f) - mean * mean;
  float inv  = rsqrtf(var + GN_EPS);
  float4 gw4 = *(const float4*)&gnw[h * 64 + l15 * 4];
  float4 gb4 = *(const float4*)&gnb[h * 64 + l15 * 4];
  float4 vb4 = *(const float4*)&vb[base];
  float4 gv4 = *(const float4*)&gvb[base];
  float gw[4] = {gw4.x, gw4.y, gw4.z, gw4.w};
  float gb[4] = {gb4.x, gb4.y, gb4.z, gb4.w};
  float vbv[4] = {vb4.x, vb4.y, vb4.z, vb4.w};
  float gvv[4] = {gv4.x, gv4.y, gv4.z, gv4.w};
  float bo = bonb[bt * HH + h];
  ushort4 hv, lv;
  unsigned short* ph = (unsigned short*)&hv;
  unsigned short* pl = (unsigned short*)&lv;
#pragma unroll
  for (int j = 0; j < 4; ++j) {
    float x = fmaf((yv[j] - mean) * inv, gw[j], gb[j]) + bo * vbv[j];
    splitu(x * gvv[j], ph[j], pl[j]);
  }
  *(ushort4*)&xoh[base] = hv;
  *(ushort4*)&xol[base] = lv;
}

// ---------------------------------------------------------------------------
extern "C" void kernel_launch(void* const* d_in, const int* in_sizes, int n_in,
                              void* d_out, int out_size, void* d_ws, size_t ws_size,
                              hipStream_t stream) {
  (void)in_sizes; (void)n_in; (void)out_size; (void)ws_size;
  const float* hid    = (const float*)d_in[0];
  const float* shift  = (const float*)d_in[1];
  const float* st0    = (const float*)d_in[2];
  const float* vfirst = (const float*)d_in[3];
  const float* xrc = (const float*)d_in[4];
  const float* xwc = (const float*)d_in[5];
  const float* xkc = (const float*)d_in[6];
  const float* xvc = (const float*)d_in[7];
  const float* xac = (const float*)d_in[8];
  const float* xgc = (const float*)d_in[9];
  const float* w0  = (const float*)d_in[10];
  const float* w1  = (const float*)d_in[11];
  const float* w2  = (const float*)d_in[12];
  const float* a0  = (const float*)d_in[13];
  const float* a1  = (const float*)d_in[14];
  const float* a2  = (const float*)d_in[15];
  const float* v0  = (const float*)d_in[16];
  const float* v1  = (const float*)d_in[17];
  const float* v2  = (const float*)d_in[18];
  const float* g1  = (const float*)d_in[19];
  const float* g2  = (const float*)d_in[20];
  const float* kkc = (const float*)d_in[21];
  const float* kac = (const float*)d_in[22];
  const float* rk  = (const float*)d_in[23];
  const float* Wr  = (const float*)d_in[24];
  const float* Wk  = (const float*)d_in[25];
  const float* Wv  = (const float*)d_in[26];
  const float* Wo  = (const float*)d_in[27];
  const float* gnw = (const float*)d_in[28];
  const float* gnb = (const float*)d_in[29];
  float* out = (float*)d_out;

  char* p = (char*)d_ws;
  auto alloc = [&](size_t n) { char* q = p; p += (n + 255) & ~(size_t)255; return q; };
  const size_t EL = (size_t)BT * CC;

  // --- alias pool: xrh..xvl + Wrh,Wrl dead by k_gate time; db/awb/bwb +
  //     h2g (the old gvb slot) overlay them.
  char* pool = p;
  __hip_bfloat16* xrh = (__hip_bfloat16*)alloc(EL * 2);
  __hip_bfloat16* xrl = (__hip_bfloat16*)alloc(EL * 2);
  __hip_bfloat16* xkh = (__hip_bfloat16*)alloc(EL * 2);
  __hip_bfloat16* xkl = (__hip_bfloat16*)alloc(EL * 2);
  __hip_bfloat16* xvh = (__hip_bfloat16*)alloc(EL * 2);
  __hip_bfloat16* xvl = (__hip_bfloat16*)alloc(EL * 2);
  __hip_bfloat16* Wrh = (__hip_bfloat16*)alloc((size_t)CC * CC * 2);
  __hip_bfloat16* Wrl = (__hip_bfloat16*)alloc((size_t)CC * CC * 2);
  float* db  = (float*)pool;           // overlays xrh+xrl
  float* awb = db + EL;                // overlays xkh+xkl
  float* bwb = db + 2 * EL;            // overlays xvh+xvl
  float* h2g = db + 3 * EL;            // overlays Wrh+Wrl (old gvb slot)

  __hip_bfloat16* Wkh = (__hip_bfloat16*)alloc((size_t)CC * CC * 2);
  __hip_bfloat16* Wkl = (__hip_bfloat16*)alloc((size_t)CC * CC * 2);
  float* ybuf = (float*)Wkh;           // overlays Wkh+Wkl (dead after k-GEMM)
  float* h2v  = (float*)Wkh;           // same region, read by k_gate BEFORE scan writes ybuf

  __hip_bfloat16* Wvh = (__hip_bfloat16*)alloc((size_t)CC * CC * 2);
  __hip_bfloat16* Wvl = (__hip_bfloat16*)alloc((size_t)CC * CC * 2);
  __hip_bfloat16* Woh = (__hip_bfloat16*)alloc((size_t)CC * CC * 2);
  __hip_bfloat16* Wol = (__hip_bfloat16*)alloc((size_t)CC * CC * 2);
  __hip_bfloat16* xw  = (__hip_bfloat16*)alloc(EL * 2);
  __hip_bfloat16* xa  = (__hip_bfloat16*)alloc(EL * 2);
  __hip_bfloat16* xg  = (__hip_bfloat16*)alloc(EL * 2);
  float* h2w = (float*)xw;             // overlays xw+xa (dead after stage-1 GEMMs)
  __hip_bfloat16* w1t = (__hip_bfloat16*)alloc((size_t)64  * CC * 2);
  __hip_bfloat16* a1t = (__hip_bfloat16*)alloc((size_t)64  * CC * 2);
  __hip_bfloat16* v1t = (__hip_bfloat16*)alloc((size_t)64  * CC * 2);
  __hip_bfloat16* g1t = (__hip_bfloat16*)alloc((size_t)128 * CC * 2);
  float* rb  = (float*)alloc(EL * 4);
  float* kb  = (float*)alloc(EL * 4);  // raw k, then k_final in place
  float* vb  = (float*)alloc(EL * 4);  // raw v, then v_mix in place
  float* h1w = (float*)alloc((size_t)BT * 64  * 4);
  float* h1a = (float*)alloc((size_t)BT * 64  * 4);
  float* h1v = (float*)alloc((size_t)BT * 64  * 4);
  float* h1g = (float*)alloc((size_t)BT * 128 * 4);
  __hip_bfloat16* xoh = (__hip_bfloat16*)alloc(EL * 2);
  __hip_bfloat16* xol = (__hip_bfloat16*)alloc(EL * 2);
  float* h2a = (float*)xoh;            // overlays xoh+xol (k_post writes them AFTER k_gate)
  float* bonb = (float*)alloc((size_t)BT * HH * 4);   // per-(token,head) bonus
  // stage-2 split operands (small, fresh):
  __hip_bfloat16* h1wh = (__hip_bfloat16*)alloc((size_t)BT * 64 * 2);
  __hip_bfloat16* h1wl = (__hip_bfloat16*)alloc((size_t)BT * 64 * 2);
  __hip_bfloat16* h1ah = (__hip_bfloat16*)alloc((size_t)BT * 64 * 2);
  __hip_bfloat16* h1al = (__hip_bfloat16*)alloc((size_t)BT * 64 * 2);
  __hip_bfloat16* h1vh = (__hip_bfloat16*)alloc((size_t)BT * 64 * 2);
  __hip_bfloat16* h1vl = (__hip_bfloat16*)alloc((size_t)BT * 64 * 2);
  __hip_bfloat16* h1gh = (__hip_bfloat16*)alloc((size_t)BT * 128 * 2);
  __hip_bfloat16* h1gl = (__hip_bfloat16*)alloc((size_t)BT * 128 * 2);
  __hip_bfloat16* w2th = (__hip_bfloat16*)alloc((size_t)CC * 64 * 2);
  __hip_bfloat16* w2tl = (__hip_bfloat16*)alloc((size_t)CC * 64 * 2);
  __hip_bfloat16* a2th = (__hip_bfloat16*)alloc((size_t)CC * 64 * 2);
  __hip_bfloat16* a2tl = (__hip_bfloat16*)alloc((size_t)CC * 64 * 2);
  __hip_bfloat16* v2th = (__hip_bfloat16*)alloc((size_t)CC * 64 * 2);
  __hip_bfloat16* v2tl = (__hip_bfloat16*)alloc((size_t)CC * 64 * 2);
  __hip_bfloat16* g2th = (__hip_bfloat16*)alloc((size_t)CC * 128 * 2);
  __hip_bfloat16* g2tl = (__hip_bfloat16*)alloc((size_t)CC * 128 * 2);
  // total ~210 MiB (known-OK envelope: 220 OK, 268 crashed)

  k_prepx<<<4096, 256, 0, stream>>>(hid, shift, xrc, xwc, xkc, xvc, xac, xgc,
                                    xrh, xrl, xw, xkh, xkl, xvh, xvl, xa, xg);
  k_cvt2x4<<<dim3(4096, 4), 256, 0, stream>>>(Wr, Wk, Wv, Wo,
                                              Wrh, Wrl, Wkh, Wkl,
                                              Wvh, Wvl, Woh, Wol);
  k_tr4<<<dim3(1024, 4), 256, 0, stream>>>(w1, a1, v1, g1, w1t, a1t, v1t, g1t);
  k_trs4<<<dim3(1024, 4), 256, 0, stream>>>(w2, a2, v2, g2,
                                            w2th, w2tl, a2th, a2tl,
                                            v2th, v2tl, g2th, g2tl);

  k_gemm_big3<<<dim3(32, 16, 3), 256, 0, stream>>>(
      xrh, xrl, Wrh, Wrl, rb,
      xkh, xkl, Wkh, Wkl, kb,
      xvh, xvl, Wvh, Wvl, vb);
  k_lora1<<<dim3(32, 5), 256, 0, stream>>>(xw, xa, xvh, xg, w1t, a1t, v1t, g1t,
                                           h1w, h1a, h1v, h1g);

  k_act2<<<256, 256, 0, stream>>>(h1w, h1a, h1v, h1g,
                                  h1wh, h1wl, h1ah, h1al,
                                  h1vh, h1vl, h1gh, h1gl);
  // stage-2 LoRA dots on MFMA (split precision), fused 4-in-1. Overlays:
  //   h2w->xw+xa, h2a->xoh+xol, h2v->Wkh+Wkl, h2g->Wrh+Wrl.
  k_gemm_s2x4<<<dim3(32, 16, 4), 256, 0, stream>>>(
      h1wh, h1wl, h1ah, h1al, h1vh, h1vl, h1gh, h1gl,
      w2th, w2tl, a2th, a2tl, v2th, v2tl, g2th, g2tl,
      h2w, h2a, h2v, h2g);

  k_gate<<<4096, 256, 0, stream>>>(h2w, h2a, h2v, w0, a0, v0, kkc, kac,
                                   kb, vb, vfirst, rb, rk, db, awb, bwb, bonb);
  k_scan<<<1024, 64, 0, stream>>>(rb, kb, db, awb, bwb, vb, st0, ybuf);
  k_post<<<4096, 256, 0, stream>>>(ybuf, vb, h2g, bonb, gnw, gnb, xoh, xol);
  k_gemm_bt3<<<dim3(32, 16), 256, 0, stream>>>(xoh, xol, Woh, Wol, out, BT, CC, CC);
}

// Round 18
// 737.430 us; speedup vs baseline: 1.0288x; 1.0288x over previous
//
#include <hip/hip_runtime.h>
#include <hip/hip_bf16.h>

// Problem constants (RWKV-7 Tmix: B=2, T=1024, C=2048, H=32, N=64)
#define BB 2
#define TT 1024
#define CC 2048
#define HH 32
#define BT 2048          // BB*TT tokens
#define GN_EPS 6.4e-4f   // 1e-5 * 8^2

typedef __attribute__((ext_vector_type(8))) __bf16 bf16x8;
typedef __attribute__((ext_vector_type(4))) float f32x4;

__device__ __forceinline__ float sigf(float x) { return 1.0f / (1.0f + expf(-x)); }

__device__ __forceinline__ void split_bf16(float x, __hip_bfloat16& hi, __hip_bfloat16& lo) {
  __hip_bfloat16 h = __float2bfloat16(x);
  hi = h;
  lo = __float2bfloat16(x - __bfloat162float(h));
}

__device__ __forceinline__ unsigned short bfb(float x) {
  union { __hip_bfloat16 h; unsigned short u; } cv;
  cv.h = __float2bfloat16(x);
  return cv.u;
}
__device__ __forceinline__ void splitu(float x, unsigned short& hi, unsigned short& lo) {
  union { __hip_bfloat16 h; unsigned short u; } cv;
  cv.h = __float2bfloat16(x);
  hi = cv.u;
  lo = bfb(x - __bfloat162float(cv.h));
}

// Sum over each aligned 16-lane group, pure DPP (no LDS pipe on the chain).
__device__ __forceinline__ float red16(float x) {
  x += __int_as_float(__builtin_amdgcn_update_dpp(
      0, __float_as_int(x), 0xB1 /*quad_perm [1,0,3,2]*/, 0xF, 0xF, true));
  x += __int_as_float(__builtin_amdgcn_update_dpp(
      0, __float_as_int(x), 0x4E /*quad_perm [2,3,0,1]*/, 0xF, 0xF, true));
  x += __int_as_float(__builtin_amdgcn_update_dpp(
      0, __float_as_int(x), 0x141 /*row_half_mirror*/, 0xF, 0xF, true));
  x += __int_as_float(__builtin_amdgcn_update_dpp(
      0, __float_as_int(x), 0x140 /*row_mirror*/, 0xF, 0xF, true));
  return x;
}

// ---------------------------------------------------------------------------
// K1: token shift + six lerped projections — 4-wide vectorized (r14 winner).
// ---------------------------------------------------------------------------
__global__ __launch_bounds__(256) void k_prepx(
    const float* __restrict__ hid, const float* __restrict__ shift,
    const float* __restrict__ xrc, const float* __restrict__ xwc,
    const float* __restrict__ xkc, const float* __restrict__ xvc,
    const float* __restrict__ xac, const float* __restrict__ xgc,
    __hip_bfloat16* __restrict__ xrh, __hip_bfloat16* __restrict__ xrl,
    __hip_bfloat16* __restrict__ xw,
    __hip_bfloat16* __restrict__ xkh, __hip_bfloat16* __restrict__ xkl,
    __hip_bfloat16* __restrict__ xvh, __hip_bfloat16* __restrict__ xvl,
    __hip_bfloat16* __restrict__ xa, __hip_bfloat16* __restrict__ xg) {
  int i4 = (blockIdx.x * 256 + threadIdx.x) * 4;   // < BT*CC
  int c  = i4 & (CC - 1);
  int bt = i4 >> 11;
  int t  = bt & (TT - 1);
  int b  = bt >> 10;
  float4 hc = *(const float4*)&hid[i4];
  float4 hp = (t == 0) ? *(const float4*)&shift[b * CC + c]
                       : *(const float4*)&hid[i4 - CC];
  float xxv[4] = {hp.x - hc.x, hp.y - hc.y, hp.z - hc.z, hp.w - hc.w};
  float hcv[4] = {hc.x, hc.y, hc.z, hc.w};
  float4 crv = *(const float4*)&xrc[c];
  float4 cwv = *(const float4*)&xwc[c];
  float4 ckv = *(const float4*)&xkc[c];
  float4 cvv = *(const float4*)&xvc[c];
  float4 cav = *(const float4*)&xac[c];
  float4 cgv = *(const float4*)&xgc[c];
  float cr[4] = {crv.x, crv.y, crv.z, crv.w};
  float cw[4] = {cwv.x, cwv.y, cwv.z, cwv.w};
  float ck[4] = {ckv.x, ckv.y, ckv.z, ckv.w};
  float cv[4] = {cvv.x, cvv.y, cvv.z, cvv.w};
  float ca[4] = {cav.x, cav.y, cav.z, cav.w};
  float cg[4] = {cgv.x, cgv.y, cgv.z, cgv.w};
  ushort4 rh, rl, kh, kl, vh, vl, wv, av, gv;
  unsigned short* prh = (unsigned short*)&rh;
  unsigned short* prl = (unsigned short*)&rl;
  unsigned short* pkh = (unsigned short*)&kh;
  unsigned short* pkl = (unsigned short*)&kl;
  unsigned short* pvh = (unsigned short*)&vh;
  unsigned short* pvl = (unsigned short*)&vl;
  unsigned short* pw  = (unsigned short*)&wv;
  unsigned short* pa  = (unsigned short*)&av;
  unsigned short* pg  = (unsigned short*)&gv;
#pragma unroll
  for (int j = 0; j < 4; ++j) {
    splitu(fmaf(xxv[j], cr[j], hcv[j]), prh[j], prl[j]);
    splitu(fmaf(xxv[j], ck[j], hcv[j]), pkh[j], pkl[j]);
    splitu(fmaf(xxv[j], cv[j], hcv[j]), pvh[j], pvl[j]);
    pw[j] = bfb(fmaf(xxv[j], cw[j], hcv[j]));
    pa[j] = bfb(fmaf(xxv[j], ca[j], hcv[j]));
    pg[j] = bfb(fmaf(xxv[j], cg[j], hcv[j]));
  }
  *(ushort4*)&xrh[i4] = rh; *(ushort4*)&xrl[i4] = rl;
  *(ushort4*)&xkh[i4] = kh; *(ushort4*)&xkl[i4] = kl;
  *(ushort4*)&xvh[i4] = vh; *(ushort4*)&xvl[i4] = vl;
  *(ushort4*)&xw[i4]  = wv; *(ushort4*)&xa[i4]  = av;
  *(ushort4*)&xg[i4]  = gv;
}

// ---------------------------------------------------------------------------
// K2: f32 -> hi+lo bf16 split for all four big weights, 4-wide vectorized.
// ---------------------------------------------------------------------------
__global__ __launch_bounds__(256) void k_cvt2x4(
    const float* __restrict__ i0, const float* __restrict__ i1,
    const float* __restrict__ i2, const float* __restrict__ i3,
    __hip_bfloat16* __restrict__ h0, __hip_bfloat16* __restrict__ l0,
    __hip_bfloat16* __restrict__ h1, __hip_bfloat16* __restrict__ l1,
    __hip_bfloat16* __restrict__ h2, __hip_bfloat16* __restrict__ l2,
    __hip_bfloat16* __restrict__ h3, __hip_bfloat16* __restrict__ l3) {
  int i4 = (blockIdx.x * 256 + threadIdx.x) * 4;
  int w = blockIdx.y;
  const float* in = (w == 0) ? i0 : (w == 1) ? i1 : (w == 2) ? i2 : i3;
  __hip_bfloat16* oh = (w == 0) ? h0 : (w == 1) ? h1 : (w == 2) ? h2 : h3;
  __hip_bfloat16* ol = (w == 0) ? l0 : (w == 1) ? l1 : (w == 2) ? l2 : l3;
  float4 v = *(const float4*)&in[i4];
  float vv[4] = {v.x, v.y, v.z, v.w};
  ushort4 hv, lv;
  unsigned short* ph = (unsigned short*)&hv;
  unsigned short* pl = (unsigned short*)&lv;
#pragma unroll
  for (int j = 0; j < 4; ++j) splitu(vv[j], ph[j], pl[j]);
  *(ushort4*)&oh[i4] = hv;
  *(ushort4*)&ol[i4] = lv;
}

// ---------------------------------------------------------------------------
// K3: fused transpose-convert of the 4 stage-1 "up" weights (one dispatch).
// ---------------------------------------------------------------------------
__global__ __launch_bounds__(256) void k_tr4(
    const float* __restrict__ w1, const float* __restrict__ a1,
    const float* __restrict__ v1, const float* __restrict__ g1,
    __hip_bfloat16* __restrict__ w1t, __hip_bfloat16* __restrict__ a1t,
    __hip_bfloat16* __restrict__ v1t, __hip_bfloat16* __restrict__ g1t) {
  int i = blockIdx.x * 256 + threadIdx.x;   // < 128*2048 max
  int y = blockIdx.y;
  const float* in; __hip_bfloat16* out; int N0, NP;
  if (y == 0)      { in = w1; out = w1t; N0 = 64;  NP = 64;  }
  else if (y == 1) { in = a1; out = a1t; N0 = 64;  NP = 64;  }
  else if (y == 2) { in = v1; out = v1t; N0 = 32;  NP = 64;  }
  else             { in = g1; out = g1t; N0 = 128; NP = 128; }
  if (i >= NP * 2048) return;
  int n = i >> 11;
  int k = i & 2047;
  float v = (n < N0) ? in[k * N0 + n] : 0.0f;
  out[i] = __float2bfloat16(v);
}

// ---------------------------------------------------------------------------
// K3b: fused transpose+split of the 4 stage-2 "down" weights (one dispatch).
// ---------------------------------------------------------------------------
__global__ __launch_bounds__(256) void k_trs4(
    const float* __restrict__ w2, const float* __restrict__ a2,
    const float* __restrict__ v2, const float* __restrict__ g2,
    __hip_bfloat16* __restrict__ w2th, __hip_bfloat16* __restrict__ w2tl,
    __hip_bfloat16* __restrict__ a2th, __hip_bfloat16* __restrict__ a2tl,
    __hip_bfloat16* __restrict__ v2th, __hip_bfloat16* __restrict__ v2tl,
    __hip_bfloat16* __restrict__ g2th, __hip_bfloat16* __restrict__ g2tl) {
  int i = blockIdx.x * 256 + threadIdx.x;   // < CC*128 max
  int y = blockIdx.y;
  const float* in; __hip_bfloat16 *oh, *ol; int N0, lgK;
  if (y == 0)      { in = w2; oh = w2th; ol = w2tl; N0 = 64;  lgK = 6; }
  else if (y == 1) { in = a2; oh = a2th; ol = a2tl; N0 = 64;  lgK = 6; }
  else if (y == 2) { in = v2; oh = v2th; ol = v2tl; N0 = 32;  lgK = 6; }
  else             { in = g2; oh = g2th; ol = g2tl; N0 = 128; lgK = 7; }
  if (i >= (CC << lgK)) return;
  int n = i >> lgK;
  int k = i & ((1 << lgK) - 1);
  float v = (k < N0) ? in[k * CC + n] : 0.0f;
  split_bf16(v, oh[i], ol[i]);
}

// ---------------------------------------------------------------------------
// K4: fused stage-1 LoRA GEMM, LDS-staged (r11 structure + r15 swizzle).
// ---------------------------------------------------------------------------
__global__ __launch_bounds__(256, 4) void k_lora1(
    const __hip_bfloat16* __restrict__ xw, const __hip_bfloat16* __restrict__ xa,
    const __hip_bfloat16* __restrict__ xv, const __hip_bfloat16* __restrict__ xg,
    const __hip_bfloat16* __restrict__ w1t, const __hip_bfloat16* __restrict__ a1t,
    const __hip_bfloat16* __restrict__ v1t, const __hip_bfloat16* __restrict__ g1t,
    float* __restrict__ h1w, float* __restrict__ h1a,
    float* __restrict__ h1v, float* __restrict__ h1g) {
  __shared__ __align__(16) __hip_bfloat16 sA[2][64 * 32], sB[2][64 * 32];
  int tid  = threadIdx.x;
  int lane = tid & 63;
  int wv   = tid >> 6;
  int l15  = lane & 15;
  int quad = lane >> 4;
  int m0 = blockIdx.x * 64;
  int bly = blockIdx.y;

  const __hip_bfloat16* Ab;
  const __hip_bfloat16* Bb;
  float* Ob;
  int os, cb;
  if (bly == 0)      { Ab = xw; Bb = w1t;            Ob = h1w; os = 64;  cb = 0;  }
  else if (bly == 1) { Ab = xa; Bb = a1t;            Ob = h1a; os = 64;  cb = 0;  }
  else if (bly == 2) { Ab = xv; Bb = v1t;            Ob = h1v; os = 64;  cb = 0;  }
  else if (bly == 3) { Ab = xg; Bb = g1t;            Ob = h1g; os = 128; cb = 0;  }
  else               { Ab = xg; Bb = g1t + 64 * CC;  Ob = h1g; os = 128; cb = 64; }

  int srow = wv * 16 + (lane >> 2);
  int scol = (((lane & 3) ^ ((lane >> 2) & 3)) * 8);   // inverse-swizzled src
  const __hip_bfloat16* gA = Ab + (size_t)(m0 + srow) * CC + scol;
  const __hip_bfloat16* gB = Bb + (size_t)srow * CC + scol;

  f32x4 z = {0.f, 0.f, 0.f, 0.f};
  f32x4 acc0 = z, acc1 = z, acc2 = z, acc3 = z;

  int sw = (quad ^ (l15 & 3)) * 8;                     // swizzled read col
  int aoff = (wv * 16 + l15) * 32 + sw;
  int boff = l15 * 32 + sw;

#define STAGE1(BUF, KO)                                                      \
  { unsigned db_ = (unsigned)(BUF) * 4096u + (unsigned)wv * 1024u;           \
    __builtin_amdgcn_global_load_lds(                                        \
        (const __attribute__((address_space(1))) void*)(gA + (KO)),          \
        (__attribute__((address_space(3))) void*)((char*)sA + db_), 16, 0, 0);\
    __builtin_amdgcn_global_load_lds(                                        \
        (const __attribute__((address_space(1))) void*)(gB + (KO)),          \
        (__attribute__((address_space(3))) void*)((char*)sB + db_), 16, 0, 0);}

  STAGE1(0, 0)
  __syncthreads();

  for (int k0 = 0; k0 < CC; k0 += 32) {
    int cur = (k0 >> 5) & 1;
    if (k0 + 32 < CC) STAGE1(cur ^ 1, k0 + 32)

    const __hip_bfloat16* pA_ = &sA[cur][0];
    const __hip_bfloat16* pB_ = &sB[cur][0];
    bf16x8 av = *(const bf16x8*)(pA_ + aoff);
    bf16x8 b0 = *(const bf16x8*)(pB_ + boff);
    bf16x8 b1 = *(const bf16x8*)(pB_ + boff + 16 * 32);
    bf16x8 b2 = *(const bf16x8*)(pB_ + boff + 32 * 32);
    bf16x8 b3 = *(const bf16x8*)(pB_ + boff + 48 * 32);

    acc0 = __builtin_amdgcn_mfma_f32_16x16x32_bf16(av, b0, acc0, 0, 0, 0);
    acc1 = __builtin_amdgcn_mfma_f32_16x16x32_bf16(av, b1, acc1, 0, 0, 0);
    acc2 = __builtin_amdgcn_mfma_f32_16x16x32_bf16(av, b2, acc2, 0, 0, 0);
    acc3 = __builtin_amdgcn_mfma_f32_16x16x32_bf16(av, b3, acc3, 0, 0, 0);

    __syncthreads();
  }
#undef STAGE1

  int row0 = m0 + wv * 16 + quad * 4;
  int colb = cb + l15;
#pragma unroll
  for (int r = 0; r < 4; ++r) {
    Ob[(size_t)(row0 + r) * os + colb +  0] = acc0[r];
    Ob[(size_t)(row0 + r) * os + colb + 16] = acc1[r];
    Ob[(size_t)(row0 + r) * os + colb + 32] = acc2[r];
    Ob[(size_t)(row0 + r) * os + colb + 48] = acc3[r];
  }
}

// ---------------------------------------------------------------------------
// K4b body: split-precision GEMM, 64x128 tile, 2-phase LDS staging —
// ROUND-25: REVERT to r16 form (best measured: 739.9 µs total, big3 220 µs).
// r17's 3-buffer counted-vmcnt ring REGRESSED (237 µs): 72KB LDS cut
// occupancy 3->2 blocks/CU and the lost TLP (m114 implicit overlap) cost
// more than the drain it removed — regime-gate confirmed: counted vmcnt
// pays only inside the full 8-phase role-split structure (m218/m230).
// Swizzle kept (r16 proved it harmless; conflicts are DMA-side, off-path).
// ---------------------------------------------------------------------------
__device__ __forceinline__ void gemm_bt3_body(
    const __hip_bfloat16* __restrict__ Ah, const __hip_bfloat16* __restrict__ Al,
    const __hip_bfloat16* __restrict__ Bh, const __hip_bfloat16* __restrict__ Bl,
    float* __restrict__ Cm, int Nn, int K) {
  __shared__ __align__(16) __hip_bfloat16 sAh[2][64 * 32],  sAl[2][64 * 32];
  __shared__ __align__(16) __hip_bfloat16 sBh[2][128 * 32], sBl[2][128 * 32];
  int tid  = threadIdx.x;
  int lane = tid & 63;
  int wv   = tid >> 6;
  int l15  = lane & 15;
  int quad = lane >> 4;
  int m0 = blockIdx.x * 64;
  int n0 = blockIdx.y * 128;

  int srowA = wv * 16 + (lane >> 2);
  int srowB = wv * 32 + (lane >> 2);
  int scol  = (((lane & 3) ^ ((lane >> 2) & 3)) * 8);  // inverse-swizzled src
  const __hip_bfloat16* gAh  = Ah + (size_t)(m0 + srowA) * K + scol;
  const __hip_bfloat16* gAl  = Al + (size_t)(m0 + srowA) * K + scol;
  const __hip_bfloat16* gBh0 = Bh + (size_t)(n0 + srowB) * K + scol;
  const __hip_bfloat16* gBh1 = Bh + (size_t)(n0 + srowB + 16) * K + scol;
  const __hip_bfloat16* gBl0 = Bl + (size_t)(n0 + srowB) * K + scol;
  const __hip_bfloat16* gBl1 = Bl + (size_t)(n0 + srowB + 16) * K + scol;

  f32x4 z = {0.f, 0.f, 0.f, 0.f};
  f32x4 acc[8];
#pragma unroll
  for (int j = 0; j < 8; ++j) acc[j] = z;

  int sw = (quad ^ (l15 & 3)) * 8;                     // swizzled read col
  int aoff = (wv * 16 + l15) * 32 + sw;
  int boff = l15 * 32 + sw;

#define STAGE(BUF, KO)                                                       \
  { unsigned dA_ = (unsigned)(BUF) * 4096u + (unsigned)wv * 1024u;           \
    unsigned dB_ = (unsigned)(BUF) * 8192u + (unsigned)wv * 2048u;           \
    __builtin_amdgcn_global_load_lds(                                        \
        (const __attribute__((address_space(1))) void*)(gAh + (KO)),         \
        (__attribute__((address_space(3))) void*)((char*)sAh + dA_), 16, 0, 0);\
    __builtin_amdgcn_global_load_lds(                                        \
        (const __attribute__((address_space(1))) void*)(gAl + (KO)),         \
        (__attribute__((address_space(3))) void*)((char*)sAl + dA_), 16, 0, 0);\
    __builtin_amdgcn_global_load_lds(                                        \
        (const __attribute__((address_space(1))) void*)(gBh0 + (KO)),        \
        (__attribute__((address_space(3))) void*)((char*)sBh + dB_), 16, 0, 0);\
    __builtin_amdgcn_global_load_lds(                                        \
        (const __attribute__((address_space(1))) void*)(gBh1 + (KO)),        \
        (__attribute__((address_space(3))) void*)((char*)sBh + dB_ + 1024u), 16, 0, 0);\
    __builtin_amdgcn_global_load_lds(                                        \
        (const __attribute__((address_space(1))) void*)(gBl0 + (KO)),        \
        (__attribute__((address_space(3))) void*)((char*)sBl + dB_), 16, 0, 0);\
    __builtin_amdgcn_global_load_lds(                                        \
        (const __attribute__((address_space(1))) void*)(gBl1 + (KO)),        \
        (__attribute__((address_space(3))) void*)((char*)sBl + dB_ + 1024u), 16, 0, 0);}

  STAGE(0, 0)
  __syncthreads();   // buf0 staged (implicit vmcnt(0) drain before barrier)

  for (int k0 = 0; k0 < K; k0 += 32) {
    int cur = (k0 >> 5) & 1;
    if (k0 + 32 < K) STAGE(cur ^ 1, k0 + 32)   // next tile in flight NOW

    const __hip_bfloat16* pA_h = &sAh[cur][0];
    const __hip_bfloat16* pA_l = &sAl[cur][0];
    const __hip_bfloat16* pB_h = &sBh[cur][0];
    const __hip_bfloat16* pB_l = &sBl[cur][0];
    bf16x8 ah = *(const bf16x8*)(pA_h + aoff);
    bf16x8 al = *(const bf16x8*)(pA_l + aoff);
#pragma unroll
    for (int j = 0; j < 8; ++j) {
      bf16x8 bh = *(const bf16x8*)(pB_h + boff + j * 16 * 32);
      bf16x8 bl = *(const bf16x8*)(pB_l + boff + j * 16 * 32);
      acc[j] = __builtin_amdgcn_mfma_f32_16x16x32_bf16(ah, bh, acc[j], 0, 0, 0);
      acc[j] = __builtin_amdgcn_mfma_f32_16x16x32_bf16(ah, bl, acc[j], 0, 0, 0);
      acc[j] = __builtin_amdgcn_mfma_f32_16x16x32_bf16(al, bh, acc[j], 0, 0, 0);
    }

    __syncthreads();   // ONE barrier: next buf staged + this buf reads done
  }
#undef STAGE

  int row0 = m0 + wv * 16 + quad * 4;
#pragma unroll
  for (int j = 0; j < 8; ++j) {
    int colb = n0 + j * 16 + l15;
#pragma unroll
    for (int r = 0; r < 4; ++r)
      Cm[(size_t)(row0 + r) * Nn + colb] = acc[j][r];
  }
}

// standalone (Wo output GEMM)
__global__ __launch_bounds__(256, 3) void k_gemm_bt3(
    const __hip_bfloat16* __restrict__ Ah, const __hip_bfloat16* __restrict__ Al,
    const __hip_bfloat16* __restrict__ Bh, const __hip_bfloat16* __restrict__ Bl,
    float* __restrict__ Cm, int M, int Nn, int K) {
  gemm_bt3_body(Ah, Al, Bh, Bl, Cm, Nn, K);
}

// 3 big input GEMMs (r/k/v) fused into one dispatch, grid z = slice.
__global__ __launch_bounds__(256, 3) void k_gemm_big3(
    const __hip_bfloat16* __restrict__ Ah0, const __hip_bfloat16* __restrict__ Al0,
    const __hip_bfloat16* __restrict__ Bh0, const __hip_bfloat16* __restrict__ Bl0,
    float* __restrict__ C0,
    const __hip_bfloat16* __restrict__ Ah1, const __hip_bfloat16* __restrict__ Al1,
    const __hip_bfloat16* __restrict__ Bh1, const __hip_bfloat16* __restrict__ Bl1,
    float* __restrict__ C1,
    const __hip_bfloat16* __restrict__ Ah2, const __hip_bfloat16* __restrict__ Al2,
    const __hip_bfloat16* __restrict__ Bh2, const __hip_bfloat16* __restrict__ Bl2,
    float* __restrict__ C2) {
  int zz = blockIdx.z;
  const __hip_bfloat16* Ah = (zz == 0) ? Ah0 : (zz == 1) ? Ah1 : Ah2;
  const __hip_bfloat16* Al = (zz == 0) ? Al0 : (zz == 1) ? Al1 : Al2;
  const __hip_bfloat16* Bh = (zz == 0) ? Bh0 : (zz == 1) ? Bh1 : Bh2;
  const __hip_bfloat16* Bl = (zz == 0) ? Bl0 : (zz == 1) ? Bl1 : Bl2;
  float* Cm = (zz == 0) ? C0 : (zz == 1) ? C1 : C2;
  gemm_bt3_body(Ah, Al, Bh, Bl, Cm, CC, CC);
}

// 4 stage-2 GEMMs fused into one dispatch, grid z = slice (K table).
__global__ __launch_bounds__(256, 3) void k_gemm_s2x4(
    const __hip_bfloat16* __restrict__ h1wh, const __hip_bfloat16* __restrict__ h1wl,
    const __hip_bfloat16* __restrict__ h1ah, const __hip_bfloat16* __restrict__ h1al,
    const __hip_bfloat16* __restrict__ h1vh, const __hip_bfloat16* __restrict__ h1vl,
    const __hip_bfloat16* __restrict__ h1gh, const __hip_bfloat16* __restrict__ h1gl,
    const __hip_bfloat16* __restrict__ w2th, const __hip_bfloat16* __restrict__ w2tl,
    const __hip_bfloat16* __restrict__ a2th, const __hip_bfloat16* __restrict__ a2tl,
    const __hip_bfloat16* __restrict__ v2th, const __hip_bfloat16* __restrict__ v2tl,
    const __hip_bfloat16* __restrict__ g2th, const __hip_bfloat16* __restrict__ g2tl,
    float* __restrict__ h2w, float* __restrict__ h2a,
    float* __restrict__ h2v, float* __restrict__ h2g) {
  int zz = blockIdx.z;
  const __hip_bfloat16* Ah = (zz == 0) ? h1wh : (zz == 1) ? h1ah : (zz == 2) ? h1vh : h1gh;
  const __hip_bfloat16* Al = (zz == 0) ? h1wl : (zz == 1) ? h1al : (zz == 2) ? h1vl : h1gl;
  const __hip_bfloat16* Bh = (zz == 0) ? w2th : (zz == 1) ? a2th : (zz == 2) ? v2th : g2th;
  const __hip_bfloat16* Bl = (zz == 0) ? w2tl : (zz == 1) ? a2tl : (zz == 2) ? v2tl : g2tl;
  float* Cm = (zz == 0) ? h2w : (zz == 1) ? h2a : (zz == 2) ? h2v : h2g;
  int K = (zz == 3) ? 128 : 64;
  gemm_bt3_body(Ah, Al, Bh, Bl, Cm, CC, K);
}

// ---------------------------------------------------------------------------
// K5: activations + hi/lo split of stage-1 LoRA outputs — 4-wide vectorized.
// ---------------------------------------------------------------------------
__global__ __launch_bounds__(256) void k_act2(
    const float* __restrict__ h1w, const float* __restrict__ h1a,
    const float* __restrict__ h1v, const float* __restrict__ h1g,
    __hip_bfloat16* __restrict__ wh, __hip_bfloat16* __restrict__ wl,
    __hip_bfloat16* __restrict__ ah, __hip_bfloat16* __restrict__ al,
    __hip_bfloat16* __restrict__ vh, __hip_bfloat16* __restrict__ vl,
    __hip_bfloat16* __restrict__ gh, __hip_bfloat16* __restrict__ gl) {
  int i4 = (blockIdx.x * 256 + threadIdx.x) * 4;   // over BT*128
  if (i4 < BT * 64) {
    float4 w = *(const float4*)&h1w[i4];
    float4 a = *(const float4*)&h1a[i4];
    float4 v = *(const float4*)&h1v[i4];
    float wvv[4] = {w.x, w.y, w.z, w.w};
    float avv[4] = {a.x, a.y, a.z, a.w};
    float vvv[4] = {v.x, v.y, v.z, v.w};
    ushort4 whv, wlv, ahv, alv, vhv, vlv;
    unsigned short* p0 = (unsigned short*)&whv;
    unsigned short* p1 = (unsigned short*)&wlv;
    unsigned short* p2 = (unsigned short*)&ahv;
    unsigned short* p3 = (unsigned short*)&alv;
    unsigned short* p4 = (unsigned short*)&vhv;
    unsigned short* p5 = (unsigned short*)&vlv;
#pragma unroll
    for (int j = 0; j < 4; ++j) {
      splitu(tanhf(wvv[j]), p0[j], p1[j]);
      splitu(avv[j], p2[j], p3[j]);
      splitu(vvv[j], p4[j], p5[j]);
    }
    *(ushort4*)&wh[i4] = whv; *(ushort4*)&wl[i4] = wlv;
    *(ushort4*)&ah[i4] = ahv; *(ushort4*)&al[i4] = alv;
    *(ushort4*)&vh[i4] = vhv; *(ushort4*)&vl[i4] = vlv;
  }
  float4 g = *(const float4*)&h1g[i4];
  float gvv[4] = {g.x, g.y, g.z, g.w};
  ushort4 ghv, glv;
  unsigned short* p6 = (unsigned short*)&ghv;
  unsigned short* p7 = (unsigned short*)&glv;
#pragma unroll
  for (int j = 0; j < 4; ++j) splitu(sigf(gvv[j]), p6[j], p7[j]);
  *(ushort4*)&gh[i4] = ghv; *(ushort4*)&gl[i4] = glv;
}

// ---------------------------------------------------------------------------
// K6: gates + kk-normalize + per-head bonus — 4-wide, red16 reductions.
// ---------------------------------------------------------------------------
__global__ __launch_bounds__(256) void k_gate(
    const float* __restrict__ h2w, const float* __restrict__ h2a,
    const float* __restrict__ h2v,
    const float* __restrict__ w0, const float* __restrict__ a0,
    const float* __restrict__ v0, const float* __restrict__ kkc,
    const float* __restrict__ kac, float* __restrict__ kbuf,
    float* __restrict__ vbuf, const float* __restrict__ vfirst,
    const float* __restrict__ rbuf, const float* __restrict__ rk,
    float* __restrict__ dec, float* __restrict__ aw,
    float* __restrict__ bw, float* __restrict__ bonb) {
  int i4 = (blockIdx.x * 256 + threadIdx.x) * 4;   // < BT*CC
  int c = i4 & (CC - 1);
  float4 kv4 = *(const float4*)&kbuf[i4];
  float4 vv4 = *(const float4*)&vbuf[i4];
  float4 vf4 = *(const float4*)&vfirst[i4];
  float4 hw4 = *(const float4*)&h2w[i4];
  float4 ha4 = *(const float4*)&h2a[i4];
  float4 hv4 = *(const float4*)&h2v[i4];
  float4 w04 = *(const float4*)&w0[c];
  float4 a04 = *(const float4*)&a0[c];
  float4 v04 = *(const float4*)&v0[c];
  float4 kk4 = *(const float4*)&kkc[c];
  float4 ka4 = *(const float4*)&kac[c];
  float4 rk4 = *(const float4*)&rk[c];
  float4 rb4 = *(const float4*)&rbuf[i4];
  float kv[4] = {kv4.x, kv4.y, kv4.z, kv4.w};
  float vv[4] = {vv4.x, vv4.y, vv4.z, vv4.w};
  float vf[4] = {vf4.x, vf4.y, vf4.z, vf4.w};
  float hw[4] = {hw4.x, hw4.y, hw4.z, hw4.w};
  float ha[4] = {ha4.x, ha4.y, ha4.z, ha4.w};
  float hv[4] = {hv4.x, hv4.y, hv4.z, hv4.w};
  float w0v[4] = {w04.x, w04.y, w04.z, w04.w};
  float a0v[4] = {a04.x, a04.y, a04.z, a04.w};
  float v0v[4] = {v04.x, v04.y, v04.z, v04.w};
  float kkv[4] = {kk4.x, kk4.y, kk4.z, kk4.w};
  float kav[4] = {ka4.x, ka4.y, ka4.z, ka4.w};
  float rkv[4] = {rk4.x, rk4.y, rk4.z, rk4.w};
  float rbv[4] = {rb4.x, rb4.y, rb4.z, rb4.w};
  float d_[4], as[4], vm[4], kfv[4], kku[4];
  float sl = 0.f, bl = 0.f;
#pragma unroll
  for (int j = 0; j < 4; ++j) {
    d_[j] = 0.60653065971f * sigf(w0v[j] + hw[j]);   // sigmoid * e^-0.5
    as[j] = sigf(a0v[j] + ha[j]);
    float vs = sigf(v0v[j] + hv[j]);
    vm[j] = vv[j] + (vf[j] - vv[j]) * vs;
    kfv[j] = kv[j] * (1.0f + kav[j] * (as[j] - 1.0f));
    kku[j] = kv[j] * kkv[j];
    sl = fmaf(kku[j], kku[j], sl);
    bl = fmaf(rbv[j] * kfv[j], rkv[j], bl);
  }
  float s = red16(sl);                 // per-head L2 (16 lanes x 4 cols)
  float nrm = fmaxf(sqrtf(s), 1e-12f);
  float bon = red16(bl);
  if ((threadIdx.x & 15) == 0) bonb[(i4 >> 11) * HH + (c >> 6)] = bon;
  float4 o0, o1, o2, o3, o4;
  float* q0 = (float*)&o0; float* q1 = (float*)&o1; float* q2 = (float*)&o2;
  float* q3 = (float*)&o3; float* q4 = (float*)&o4;
#pragma unroll
  for (int j = 0; j < 4; ++j) {
    float kkn = kku[j] / nrm;
    q0[j] = d_[j];
    q1[j] = -kkn;
    q2[j] = kkn * as[j];
    q3[j] = kfv[j];
    q4[j] = vm[j];
  }
  *(float4*)&dec[i4] = o0;
  *(float4*)&aw[i4]  = o1;
  *(float4*)&bw[i4]  = o2;
  *(float4*)&kbuf[i4] = o3;
  *(float4*)&vbuf[i4] = o4;
}

// ---------------------------------------------------------------------------
// K7: WKV7 scan — r13 counted-lgkm LDS-DMA-ring version (~180 µs), unchanged.
// ---------------------------------------------------------------------------
__global__ __launch_bounds__(64, 1) void k_scan(
    const float* __restrict__ rbuf, const float* __restrict__ kf,
    const float* __restrict__ dec, const float* __restrict__ aw,
    const float* __restrict__ bw, const float* __restrict__ vbuf,
    const float* __restrict__ st0, float* __restrict__ ybuf) {
  __shared__ __align__(16) char ldsbuf[16 * 2048];
  int blk = blockIdx.x;                     // 0..1023
  int xcd = blk & 7;
  int q   = blk >> 3;                       // 0..127
  int bh  = xcd * 8 + (q & 7);              // 16 rg-waves of a head share blk%8
  int rg  = q >> 3;                         // 0..15
  int b = bh >> 5, h = bh & 31;
  int lane = threadIdx.x;
  int l15  = lane & 15;
  int row  = rg * 4 + (lane >> 4);
  size_t tokbase = (size_t)b * TT * CC + h * 64;

  f32x4 S = *(const f32x4*)(st0 + ((size_t)bh * 64 + row) * 64 + l15 * 4);
  bool writer = (l15 == 0);
  float* yout = ybuf + tokbase + row;

  const float* g1 = (lane < 16 ? rbuf : lane < 32 ? kf : lane < 48 ? dec : aw)
                  + tokbase + l15 * 4;
  const float* g2 = (lane < 16) ? (bw + tokbase + l15 * 4)
                                : (vbuf + tokbase + rg * 4);

  unsigned lbase = (unsigned)(uintptr_t)(__attribute__((address_space(3))) char*)ldsbuf;
  unsigned larr = lbase + (unsigned)(l15 * 16);
  unsigned lvad = lbase + 1280u + (unsigned)((lane >> 4) * 4);

#define DMAQ(T)                                                              \
  { char* sb_ = ldsbuf + (((T) & 15) << 11);                                 \
    __builtin_amdgcn_global_load_lds(                                        \
        (const __attribute__((address_space(1))) void*)g1,                   \
        (__attribute__((address_space(3))) void*)sb_, 16, 0, 0);             \
    __builtin_amdgcn_global_load_lds(                                        \
        (const __attribute__((address_space(1))) void*)g2,                   \
        (__attribute__((address_space(3))) void*)(sb_ + 1024), 16, 0, 0);    \
    g1 += CC; g2 += CC; }

#define DSRD(RR, RK, RD, RA, RB, RV, T)                                      \
  { unsigned a_ = larr + (unsigned)(((T) & 15) << 11);                       \
    unsigned v_ = lvad + (unsigned)(((T) & 15) << 11);                       \
    asm volatile("ds_read_b128 %0, %1"             : "=v"(RR) : "v"(a_));    \
    asm volatile("ds_read_b128 %0, %1 offset:256"  : "=v"(RK) : "v"(a_));    \
    asm volatile("ds_read_b128 %0, %1 offset:512"  : "=v"(RD) : "v"(a_));    \
    asm volatile("ds_read_b128 %0, %1 offset:768"  : "=v"(RA) : "v"(a_));    \
    asm volatile("ds_read_b128 %0, %1 offset:1024" : "=v"(RB) : "v"(a_));    \
    asm volatile("ds_read_b32 %0, %1"              : "=v"(RV) : "v"(v_)); }

#define WVM(N) { asm volatile("s_waitcnt vmcnt(" #N ")" ::: "memory");       \
                 __builtin_amdgcn_sched_barrier(0); }
#define WLG    { asm volatile("s_waitcnt lgkmcnt(0)" ::: "memory");          \
                 __builtin_amdgcn_sched_barrier(0); }
#define WLG6   { asm volatile("s_waitcnt lgkmcnt(6)" ::: "memory");          \
                 __builtin_amdgcn_sched_barrier(0); }

#define STEPR(RR, RK, RD, RA, RB, RV, T)                                     \
  { float sa = fmaf(S.w, RA.w, fmaf(S.z, RA.z,                               \
               fmaf(S.y, RA.y, S.x * RA.x)));                                \
    sa = red16(sa);                                                          \
    float vv = RV;                                                           \
    S.x = fmaf(S.x, RD.x, fmaf(sa, RB.x, vv * RK.x));                        \
    S.y = fmaf(S.y, RD.y, fmaf(sa, RB.y, vv * RK.y));                        \
    S.z = fmaf(S.z, RD.z, fmaf(sa, RB.z, vv * RK.z));                        \
    S.w = fmaf(S.w, RD.w, fmaf(sa, RB.w, vv * RK.w));                        \
    float y = fmaf(S.w, RR.w, fmaf(S.z, RR.z,                                \
              fmaf(S.y, RR.y, S.x * RR.x)));                                 \
    y = red16(y);                                                            \
    if (writer) yout[(size_t)(T) * CC] = y; }

  for (int tt = 0; tt < 16; ++tt) DMAQ(tt)

  f32x4 Ar, Ak, Ad, Aa, Ab; float Av;
  f32x4 Br, Bk, Bd, Ba, Bb; float Bv;

  WVM(24)
  DSRD(Ar, Ak, Ad, Aa, Ab, Av, 0)
  WLG
  DSRD(Br, Bk, Bd, Ba, Bb, Bv, 1)

  int t = 0;
  for (; t < TT - 16; t += 2) {
    DMAQ(t + 16)
    STEPR(Ar, Ak, Ad, Aa, Ab, Av, t)
    DSRD(Ar, Ak, Ad, Aa, Ab, Av, t + 2)
    WLG6
    DMAQ(t + 17)
    STEPR(Br, Bk, Bd, Ba, Bb, Bv, t + 1)
    DSRD(Br, Bk, Bd, Ba, Bb, Bv, t + 3)
    WLG6
  }
  for (; t < TT - 2; t += 2) {
    STEPR(Ar, Ak, Ad, Aa, Ab, Av, t)
    DSRD(Ar, Ak, Ad, Aa, Ab, Av, t + 2)
    WLG6
    STEPR(Br, Bk, Bd, Ba, Bb, Bv, t + 1)
    if (t + 3 < TT) DSRD(Br, Bk, Bd, Ba, Bb, Bv, t + 3)
    WLG6
  }
  STEPR(Ar, Ak, Ad, Aa, Ab, Av, TT - 2)
  WLG
  STEPR(Br, Bk, Bd, Ba, Bb, Bv, TT - 1)
#undef DMAQ
#undef DSRD
#undef WVM
#undef WLG
#undef WLG6
#undef STEPR
}

// ---------------------------------------------------------------------------
// K8: post-scan epilogue — 4-wide, red16 statistics.
// ---------------------------------------------------------------------------
__global__ __launch_bounds__(256) void k_post(
    const float* __restrict__ ybuf, const float* __restrict__ vb,
    const float* __restrict__ gvb, const float* __restrict__ bonb,
    const float* __restrict__ gnw, const float* __restrict__ gnb,
    __hip_bfloat16* __restrict__ xoh, __hip_bfloat16* __restrict__ xol) {
  int gid = blockIdx.x * 16 + (threadIdx.x >> 4);   // 0..BT*HH-1
  int l15 = threadIdx.x & 15;
  int bt = gid >> 5, h = gid & 31;
  size_t base = (size_t)bt * CC + h * 64 + l15 * 4;
  float4 y4 = *(const float4*)&ybuf[base];
  float yv[4] = {y4.x, y4.y, y4.z, y4.w};
  float s1 = yv[0] + yv[1] + yv[2] + yv[3];
  float s2 = fmaf(yv[0], yv[0], fmaf(yv[1], yv[1],
             fmaf(yv[2], yv[2], yv[3] * yv[3])));
  s1 = red16(s1);
  s2 = red16(s2);
  float mean = s1 * (1.0f / 64.0f);
  float var  = s2 * (1.0f / 64.0f) - mean * mean;
  float inv  = rsqrtf(var + GN_EPS);
  float4 gw4 = *(const float4*)&gnw[h * 64 + l15 * 4];
  float4 gb4 = *(const float4*)&gnb[h * 64 + l15 * 4];
  float4 vb4 = *(const float4*)&vb[base];
  float4 gv4 = *(const float4*)&gvb[base];
  float gw[4] = {gw4.x, gw4.y, gw4.z, gw4.w};
  float gb[4] = {gb4.x, gb4.y, gb4.z, gb4.w};
  float vbv[4] = {vb4.x, vb4.y, vb4.z, vb4.w};
  float gvv[4] = {gv4.x, gv4.y, gv4.z, gv4.w};
  float bo = bonb[bt * HH + h];
  ushort4 hv, lv;
  unsigned short* ph = (unsigned short*)&hv;
  unsigned short* pl = (unsigned short*)&lv;
#pragma unroll
  for (int j = 0; j < 4; ++j) {
    float x = fmaf((yv[j] - mean) * inv, gw[j], gb[j]) + bo * vbv[j];
    splitu(x * gvv[j], ph[j], pl[j]);
  }
  *(ushort4*)&xoh[base] = hv;
  *(ushort4*)&xol[base] = lv;
}

// ---------------------------------------------------------------------------
extern "C" void kernel_launch(void* const* d_in, const int* in_sizes, int n_in,
                              void* d_out, int out_size, void* d_ws, size_t ws_size,
                              hipStream_t stream) {
  (void)in_sizes; (void)n_in; (void)out_size; (void)ws_size;
  const float* hid    = (const float*)d_in[0];
  const float* shift  = (const float*)d_in[1];
  const float* st0    = (const float*)d_in[2];
  const float* vfirst = (const float*)d_in[3];
  const float* xrc = (const float*)d_in[4];
  const float* xwc = (const float*)d_in[5];
  const float* xkc = (const float*)d_in[6];
  const float* xvc = (const float*)d_in[7];
  const float* xac = (const float*)d_in[8];
  const float* xgc = (const float*)d_in[9];
  const float* w0  = (const float*)d_in[10];
  const float* w1  = (const float*)d_in[11];
  const float* w2  = (const float*)d_in[12];
  const float* a0  = (const float*)d_in[13];
  const float* a1  = (const float*)d_in[14];
  const float* a2  = (const float*)d_in[15];
  const float* v0  = (const float*)d_in[16];
  const float* v1  = (const float*)d_in[17];
  const float* v2  = (const float*)d_in[18];
  const float* g1  = (const float*)d_in[19];
  const float* g2  = (const float*)d_in[20];
  const float* kkc = (const float*)d_in[21];
  const float* kac = (const float*)d_in[22];
  const float* rk  = (const float*)d_in[23];
  const float* Wr  = (const float*)d_in[24];
  const float* Wk  = (const float*)d_in[25];
  const float* Wv  = (const float*)d_in[26];
  const float* Wo  = (const float*)d_in[27];
  const float* gnw = (const float*)d_in[28];
  const float* gnb = (const float*)d_in[29];
  float* out = (float*)d_out;

  char* p = (char*)d_ws;
  auto alloc = [&](size_t n) { char* q = p; p += (n + 255) & ~(size_t)255; return q; };
  const size_t EL = (size_t)BT * CC;

  // --- alias pool: xrh..xvl + Wrh,Wrl dead by k_gate time; db/awb/bwb +
  //     h2g (the old gvb slot) overlay them.
  char* pool = p;
  __hip_bfloat16* xrh = (__hip_bfloat16*)alloc(EL * 2);
  __hip_bfloat16* xrl = (__hip_bfloat16*)alloc(EL * 2);
  __hip_bfloat16* xkh = (__hip_bfloat16*)alloc(EL * 2);
  __hip_bfloat16* xkl = (__hip_bfloat16*)alloc(EL * 2);
  __hip_bfloat16* xvh = (__hip_bfloat16*)alloc(EL * 2);
  __hip_bfloat16* xvl = (__hip_bfloat16*)alloc(EL * 2);
  __hip_bfloat16* Wrh = (__hip_bfloat16*)alloc((size_t)CC * CC * 2);
  __hip_bfloat16* Wrl = (__hip_bfloat16*)alloc((size_t)CC * CC * 2);
  float* db  = (float*)pool;           // overlays xrh+xrl
  float* awb = db + EL;                // overlays xkh+xkl
  float* bwb = db + 2 * EL;            // overlays xvh+xvl
  float* h2g = db + 3 * EL;            // overlays Wrh+Wrl (old gvb slot)

  __hip_bfloat16* Wkh = (__hip_bfloat16*)alloc((size_t)CC * CC * 2);
  __hip_bfloat16* Wkl = (__hip_bfloat16*)alloc((size_t)CC * CC * 2);
  float* ybuf = (float*)Wkh;           // overlays Wkh+Wkl (dead after k-GEMM)
  float* h2v  = (float*)Wkh;           // same region, read by k_gate BEFORE scan writes ybuf

  __hip_bfloat16* Wvh = (__hip_bfloat16*)alloc((size_t)CC * CC * 2);
  __hip_bfloat16* Wvl = (__hip_bfloat16*)alloc((size_t)CC * CC * 2);
  __hip_bfloat16* Woh = (__hip_bfloat16*)alloc((size_t)CC * CC * 2);
  __hip_bfloat16* Wol = (__hip_bfloat16*)alloc((size_t)CC * CC * 2);
  __hip_bfloat16* xw  = (__hip_bfloat16*)alloc(EL * 2);
  __hip_bfloat16* xa  = (__hip_bfloat16*)alloc(EL * 2);
  __hip_bfloat16* xg  = (__hip_bfloat16*)alloc(EL * 2);
  float* h2w = (float*)xw;             // overlays xw+xa (dead after stage-1 GEMMs)
  __hip_bfloat16* w1t = (__hip_bfloat16*)alloc((size_t)64  * CC * 2);
  __hip_bfloat16* a1t = (__hip_bfloat16*)alloc((size_t)64  * CC * 2);
  __hip_bfloat16* v1t = (__hip_bfloat16*)alloc((size_t)64  * CC * 2);
  __hip_bfloat16* g1t = (__hip_bfloat16*)alloc((size_t)128 * CC * 2);
  float* rb  = (float*)alloc(EL * 4);
  float* kb  = (float*)alloc(EL * 4);  // raw k, then k_final in place
  float* vb  = (float*)alloc(EL * 4);  // raw v, then v_mix in place
  float* h1w = (float*)alloc((size_t)BT * 64  * 4);
  float* h1a = (float*)alloc((size_t)BT * 64  * 4);
  float* h1v = (float*)alloc((size_t)BT * 64  * 4);
  float* h1g = (float*)alloc((size_t)BT * 128 * 4);
  __hip_bfloat16* xoh = (__hip_bfloat16*)alloc(EL * 2);
  __hip_bfloat16* xol = (__hip_bfloat16*)alloc(EL * 2);
  float* h2a = (float*)xoh;            // overlays xoh+xol (k_post writes them AFTER k_gate)
  float* bonb = (float*)alloc((size_t)BT * HH * 4);   // per-(token,head) bonus
  // stage-2 split operands (small, fresh):
  __hip_bfloat16* h1wh = (__hip_bfloat16*)alloc((size_t)BT * 64 * 2);
  __hip_bfloat16* h1wl = (__hip_bfloat16*)alloc((size_t)BT * 64 * 2);
  __hip_bfloat16* h1ah = (__hip_bfloat16*)alloc((size_t)BT * 64 * 2);
  __hip_bfloat16* h1al = (__hip_bfloat16*)alloc((size_t)BT * 64 * 2);
  __hip_bfloat16* h1vh = (__hip_bfloat16*)alloc((size_t)BT * 64 * 2);
  __hip_bfloat16* h1vl = (__hip_bfloat16*)alloc((size_t)BT * 64 * 2);
  __hip_bfloat16* h1gh = (__hip_bfloat16*)alloc((size_t)BT * 128 * 2);
  __hip_bfloat16* h1gl = (__hip_bfloat16*)alloc((size_t)BT * 128 * 2);
  __hip_bfloat16* w2th = (__hip_bfloat16*)alloc((size_t)CC * 64 * 2);
  __hip_bfloat16* w2tl = (__hip_bfloat16*)alloc((size_t)CC * 64 * 2);
  __hip_bfloat16* a2th = (__hip_bfloat16*)alloc((size_t)CC * 64 * 2);
  __hip_bfloat16* a2tl = (__hip_bfloat16*)alloc((size_t)CC * 64 * 2);
  __hip_bfloat16* v2th = (__hip_bfloat16*)alloc((size_t)CC * 64 * 2);
  __hip_bfloat16* v2tl = (__hip_bfloat16*)alloc((size_t)CC * 64 * 2);
  __hip_bfloat16* g2th = (__hip_bfloat16*)alloc((size_t)CC * 128 * 2);
  __hip_bfloat16* g2tl = (__hip_bfloat16*)alloc((size_t)CC * 128 * 2);
  // total ~210 MiB (known-OK envelope: 220 OK, 268 crashed)

  k_prepx<<<4096, 256, 0, stream>>>(hid, shift, xrc, xwc, xkc, xvc, xac, xgc,
                                    xrh, xrl, xw, xkh, xkl, xvh, xvl, xa, xg);
  k_cvt2x4<<<dim3(4096, 4), 256, 0, stream>>>(Wr, Wk, Wv, Wo,
                                              Wrh, Wrl, Wkh, Wkl,
                                              Wvh, Wvl, Woh, Wol);
  k_tr4<<<dim3(1024, 4), 256, 0, stream>>>(w1, a1, v1, g1, w1t, a1t, v1t, g1t);
  k_trs4<<<dim3(1024, 4), 256, 0, stream>>>(w2, a2, v2, g2,
                                            w2th, w2tl, a2th, a2tl,
                                            v2th, v2tl, g2th, g2tl);

  k_gemm_big3<<<dim3(32, 16, 3), 256, 0, stream>>>(
      xrh, xrl, Wrh, Wrl, rb,
      xkh, xkl, Wkh, Wkl, kb,
      xvh, xvl, Wvh, Wvl, vb);
  k_lora1<<<dim3(32, 5), 256, 0, stream>>>(xw, xa, xvh, xg, w1t, a1t, v1t, g1t,
                                           h1w, h1a, h1v, h1g);

  k_act2<<<256, 256, 0, stream>>>(h1w, h1a, h1v, h1g,
                                  h1wh, h1wl, h1ah, h1al,
                                  h1vh, h1vl, h1gh, h1gl);
  // stage-2 LoRA dots on MFMA (split precision), fused 4-in-1. Overlays:
  //   h2w->xw+xa, h2a->xoh+xol, h2v->Wkh+Wkl, h2g->Wrh+Wrl.
  k_gemm_s2x4<<<dim3(32, 16, 4), 256, 0, stream>>>(
      h1wh, h1wl, h1ah, h1al, h1vh, h1vl, h1gh, h1gl,
      w2th, w2tl, a2th, a2tl, v2th, v2tl, g2th, g2tl,
      h2w, h2a, h2v, h2g);

  k_gate<<<4096, 256, 0, stream>>>(h2w, h2a, h2v, w0, a0, v0, kkc, kac,
                                   kb, vb, vfirst, rb, rk, db, awb, bwb, bonb);
  k_scan<<<1024, 64, 0, stream>>>(rb, kb, db, awb, bwb, vb, st0, ybuf);
  k_post<<<4096, 256, 0, stream>>>(ybuf, vb, h2g, bonb, gnw, gnb, xoh, xol);
  k_gemm_bt3<<<dim3(32, 16), 256, 0, stream>>>(xoh, xol, Woh, Wol, out, BT, CC, CC);
}